// Round 4
// baseline (530.344 us; speedup 1.0000x reference)
//
#include <hip/hip_runtime.h>

typedef unsigned short u16;
typedef unsigned int   u32;
typedef __attribute__((ext_vector_type(8)))  __bf16 bf16x8;
typedef __attribute__((ext_vector_type(4)))  float  f32x4;
typedef __attribute__((ext_vector_type(16))) float  f32x16;
typedef __attribute__((ext_vector_type(4)))  u32    u32x4;

#define F_DIM   1152
#define QKV_DIM 3456
#define HD_SCALE 0.083333333333333333f   // 1/sqrt(144)
#define LOG2E    1.4426950408889634f

static __device__ __forceinline__ u16 f2bf(float f){
    u32 u = __builtin_bit_cast(u32, f);
    u32 r = u + 0x7fffu + ((u >> 16) & 1u);   // RNE
    return (u16)(r >> 16);
}
static __device__ __forceinline__ float bf2f(u16 h){
    u32 u = ((u32)h) << 16;
    return __builtin_bit_cast(float, u);
}
static __device__ __forceinline__ u32 pack2(float a, float b){
    return (u32)f2bf(a) | ((u32)f2bf(b) << 16);
}

typedef __attribute__((address_space(1))) void gvoid;
typedef __attribute__((address_space(3))) void lvoid;
static __device__ __forceinline__ void gload16(const u16* g, u16* l){
    __builtin_amdgcn_global_load_lds((gvoid*)g, (lvoid*)l, 16, 0, 0);
}

// ---------------------------------------------------------------------------
// meta: [0]=ntiles  [1..17]=graph offsets  [20..36]=padded V col starts
//       [40..56]=bias block offsets  [64+i]=tile graph  [64+MAXT+i]=tile q idx
// ---------------------------------------------------------------------------
__global__ void setup_meta(const int* __restrict__ batch, int* __restrict__ meta,
                           int N, int maxTiles){
    int t = threadIdx.x;
    if (t <= 16){
        int lo = 0, hi = N;
        while (lo < hi){ int mid = (lo+hi)>>1; if (batch[mid] < t) lo = mid+1; else hi = mid; }
        meta[1+t] = lo;
    }
    __syncthreads();
    if (t == 0){
        int cnt = 0, ps = 0, bcnt = 0;
        for (int g = 0; g < 16; g++){
            int ng = meta[2+g] - meta[1+g];
            meta[20+g] = ps;
            meta[40+g] = bcnt;
            int nt = (ng + 31) / 32;
            ps += nt * 32;
            bcnt += nt * nt;
            for (int q = 0; q < nt; q++){
                meta[64 + cnt] = g;
                meta[64 + maxTiles + cnt] = q;
                cnt++;
            }
        }
        meta[36] = ps;
        meta[56] = bcnt;
        meta[0]  = cnt;
    }
}

__global__ __launch_bounds__(256) void cast_f32_bf16(const float* __restrict__ in,
                                                     u16* __restrict__ out, int n4){
    int i = blockIdx.x*256 + threadIdx.x;
    if (i < n4){
        float4 v = ((const float4*)in)[i];
        ((ushort4*)out)[i] = make_ushort4(f2bf(v.x), f2bf(v.y), f2bf(v.z), f2bf(v.w));
    }
}

__global__ __launch_bounds__(256) void transpose_cast(const float* __restrict__ in,
                                                      u16* __restrict__ out, int R, int C){
    __shared__ float tile[32][33];
    int c0 = blockIdx.x*32, r0 = blockIdx.y*32;
    int tx = threadIdx.x & 31, ty = threadIdx.x >> 5;
    #pragma unroll
    for (int yy = ty; yy < 32; yy += 8){
        int r = r0+yy, c = c0+tx;
        tile[yy][tx] = (r < R && c < C) ? in[(size_t)r*C + c] : 0.f;
    }
    __syncthreads();
    #pragma unroll
    for (int yy = ty; yy < 32; yy += 8){
        int oc = c0+yy, orr = r0+tx;
        if (oc < C && orr < R) out[(size_t)oc*R + orr] = f2bf(tile[tx][yy]);
    }
}

// ---------------------------------------------------------------------------
// C[M,Ncols] = A[M,K] * Bt[Ncols,K]^T ; 128x128 tile, BK=32, global_load_lds,
// XCD-aware bijective swizzle.
// ---------------------------------------------------------------------------
template<bool OUT_BF16>
__global__ __launch_bounds__(256) void gemm128(const u16* __restrict__ A,
                                               const u16* __restrict__ Bt,
                                               void* __restrict__ Cp,
                                               int M, int Ncols, int K){
    __shared__ u16 sA[128*32];
    __shared__ u16 sB[128*32];
    const int nwg = gridDim.x * gridDim.y;
    int orig = blockIdx.y * gridDim.x + blockIdx.x;
    int qq = nwg >> 3, rr = nwg & 7;
    int xcd = orig & 7, pos = orig >> 3;
    int nid = (xcd < rr ? xcd*(qq+1) : rr*(qq+1) + (xcd-rr)*qq) + pos;
    const int bm = (nid % gridDim.x) * 128, bn = (nid / gridDim.x) * 128;

    const int t = threadIdx.x;
    const int lane = t & 63, w = t >> 6;
    const int wr = w >> 1, wc = w & 1;
    const int fr = lane & 15, fq = lane >> 4;

    f32x16 accf[4];
    #pragma unroll
    for (int m = 0; m < 4; m++)
        #pragma unroll
        for (int e = 0; e < 16; e++) accf[m][e] = 0.f;

    const u16* aptr = A  + (size_t)(bm + (t>>2))*K + ((t&3)<<3);
    const u16* bptr = Bt + (size_t)(bn + (t>>2))*K + ((t&3)<<3);
    const size_t half = (size_t)64*K;

    for (int k0 = 0; k0 < K; k0 += 32){
        __syncthreads();
        gload16(aptr + k0,        &sA[t*8]);
        gload16(aptr + k0 + half, &sA[2048 + t*8]);
        gload16(bptr + k0,        &sB[t*8]);
        gload16(bptr + k0 + half, &sB[2048 + t*8]);
        __syncthreads();
        bf16x8 af[4], bfr[4];
        #pragma unroll
        for (int m = 0; m < 4; m++) af[m]  = *(const bf16x8*)(&sA[(wr*64 + m*16 + fr)*32 + fq*8]);
        #pragma unroll
        for (int n = 0; n < 4; n++) bfr[n] = *(const bf16x8*)(&sB[(wc*64 + n*16 + fr)*32 + fq*8]);
        #pragma unroll
        for (int m = 0; m < 4; m++){
            #pragma unroll
            for (int n = 0; n < 4; n++){
                f32x4 a; a[0]=accf[m][n*4+0]; a[1]=accf[m][n*4+1]; a[2]=accf[m][n*4+2]; a[3]=accf[m][n*4+3];
                a = __builtin_amdgcn_mfma_f32_16x16x32_bf16(af[m], bfr[n], a, 0, 0, 0);
                accf[m][n*4+0]=a[0]; accf[m][n*4+1]=a[1]; accf[m][n*4+2]=a[2]; accf[m][n*4+3]=a[3];
            }
        }
    }
    #pragma unroll
    for (int m = 0; m < 4; m++)
        #pragma unroll
        for (int n = 0; n < 4; n++)
            #pragma unroll
            for (int r = 0; r < 4; r++){
                int row = bm + wr*64 + m*16 + fq*4 + r;
                int col = bn + wc*64 + n*16 + fr;
                float v = accf[m][n*4+r];
                if (OUT_BF16) ((u16*)Cp)[(size_t)row*Ncols + col] = f2bf(v);
                else          ((float*)Cp)[(size_t)row*Ncols + col] = v;
            }
}

// ---------------------------------------------------------------------------
// VT[h][d][pcol] = v[node][h*144+d]
// ---------------------------------------------------------------------------
__global__ __launch_bounds__(256) void build_vt(const u16* __restrict__ qkv,
                                                u16* __restrict__ VT,
                                                const int* __restrict__ batch,
                                                const int* __restrict__ meta,
                                                int N, int PN){
    __shared__ u16 tile[32][33];
    int nt0 = blockIdx.x*32, dt0 = blockIdx.y*32, h = blockIdx.z;
    int tx = threadIdx.x & 31, ty = threadIdx.x >> 5;
    #pragma unroll
    for (int yy = ty; yy < 32; yy += 8){
        int node = nt0+yy, d = dt0+tx;
        tile[yy][tx] = (d < 144) ? qkv[(size_t)node*QKV_DIM + 2*F_DIM + h*144 + d] : (u16)0;
    }
    __syncthreads();
    int node = nt0 + tx;
    int g = batch[node];
    int col = meta[20+g] + (node - meta[1+g]);
    #pragma unroll
    for (int yy = ty; yy < 32; yy += 8){
        int d = dt0+yy;
        if (d < 144) VT[((size_t)h*144 + d)*PN + col] = tile[tx][yy];
    }
}

// ---------------------------------------------------------------------------
// Fourier bias precompute, cos shared across heads.
// bias[block(g,qt,jt)*8192 + h*1024 + j*32 + i]  (bf16)
// ---------------------------------------------------------------------------
__global__ __launch_bounds__(256) void bias_kernel(const float* __restrict__ pos,
                                                   const float* __restrict__ rfreq,
                                                   const float* __restrict__ Wrope,
                                                   const int* __restrict__ meta,
                                                   u16* __restrict__ bias){
    float absf[16], w[16][8];
    #pragma unroll
    for (int r = 0; r < 16; r++){
        absf[r] = fabsf(rfreq[r]);
        #pragma unroll
        for (int h = 0; h < 8; h++) w[r][h] = Wrope[r*8 + h];
    }
    const int total = meta[56];
    const int t = threadIdx.x;
    for (int bb = blockIdx.x; bb < total; bb += gridDim.x){
        int g = 0;
        while (meta[40 + g + 1] <= bb) g++;
        int rem  = bb - meta[40 + g];
        int goff = meta[1+g];
        int ng   = meta[2+g] - goff;
        int ntg  = (ng + 31) >> 5;
        int qt   = rem / ntg;
        int jt   = rem - qt*ntg;
        size_t base = (size_t)bb * 8192;
        #pragma unroll
        for (int pp = 0; pp < 4; pp++){
            int p = t + pp*256;
            int qn = goff + qt*32 + (p & 31);  if (qn >= goff + ng) qn = goff + ng - 1;
            int kn = goff + jt*32 + (p >> 5);  if (kn >= goff + ng) kn = goff + ng - 1;
            float dx = pos[qn*3+0] - pos[kn*3+0];
            float dy = pos[qn*3+1] - pos[kn*3+1];
            float dz = pos[qn*3+2] - pos[kn*3+2];
            float d  = sqrtf(dx*dx + dy*dy + dz*dz);
            float b[8];
            #pragma unroll
            for (int h = 0; h < 8; h++) b[h] = 0.f;
            #pragma unroll
            for (int r = 0; r < 16; r++){
                float c = __cosf(d * absf[r]);
                #pragma unroll
                for (int h = 0; h < 8; h++) b[h] = fmaf(c, w[r][h], b[h]);
            }
            #pragma unroll
            for (int h = 0; h < 8; h++)
                bias[base + h*1024 + p] = f2bf(b[h]);
        }
    }
}

// ---------------------------------------------------------------------------
// Flash attention, split-KV x4: one block = (q-tile, head), 4 waves.
// Wave w processes KV tiles t = w, w+4, ... independently (K/V from L2),
// then the 4 partials (m,l,O) merge through LDS. Grid is 1-D MAXT*8 with
// XCD-chunked decode: XCD x <-> head x (per-XCD L2 holds one head's K/V).
// ---------------------------------------------------------------------------
__global__ __launch_bounds__(256) void attn_kernel(
        const u16* __restrict__ qkv, const u16* __restrict__ VT,
        const u16* __restrict__ bias, u16* __restrict__ attn_out,
        const int* __restrict__ meta, int PN, int MAXT){
    __shared__ float sml[2][4][32];
    __shared__ float sfac[4][32];
    __shared__ float sLinv[32];
    __shared__ float sO[4][64][17];    // +1 pad: conflict-free merge

    // XCD-chunked bijective decode (gridDim.x = MAXT*8, divisible by 8)
    const int q8 = gridDim.x >> 3;
    const int work = ((int)blockIdx.x & 7)*q8 + ((int)blockIdx.x >> 3);
    const int h = work / MAXT;
    const int tile = work - h*MAXT;
    if (tile >= meta[0]) return;

    const int g    = meta[64 + tile];
    const int qt   = meta[64 + MAXT + tile];
    const int goff = meta[1+g], gend = meta[2+g];
    const int ng   = gend - goff;
    const int ntg  = (ng + 31) >> 5;
    const int qbase = goff + qt*32;
    const int pst  = meta[20+g];
    const int boffg= meta[40+g];

    const int tid = threadIdx.x;
    const int w = tid >> 6, lane = tid & 63;
    const int li = lane & 31, hi = lane >> 5;

    int qnode = qbase + li; if (qnode >= gend) qnode = gend - 1;
    const u16* qrow = qkv + (size_t)qnode*QKV_DIM + h*144;
    bf16x8 qf[9];
    #pragma unroll
    for (int kk = 0; kk < 9; kk++) qf[kk] = *(const bf16x8*)(qrow + kk*16 + hi*8);

    int jlr[16];
    #pragma unroll
    for (int r = 0; r < 16; r++) jlr[r] = (r & 3) + ((r >> 2) << 3) + (hi << 2);

    const u16* bbase = bias + ((size_t)boffg + (size_t)qt*ntg)*8192 + h*1024 + li;

    float mrun = -INFINITY, lrun = 0.f;
    f32x16 O[5];
    #pragma unroll
    for (int dt = 0; dt < 5; dt++)
        #pragma unroll
        for (int e = 0; e < 16; e++) O[dt][e] = 0.f;

    #pragma unroll 1
    for (int t = w; t < ntg; t += 4){
        const int j0 = t*32;
        // bias loads issued early, consumed after QK chain
        const u16* bt = bbase + (size_t)t*8192;
        u16 braw[16];
        #pragma unroll
        for (int r = 0; r < 16; r++) braw[r] = bt[jlr[r]*32];

        int knc = ((j0 + li) < ng) ? (goff + j0 + li) : (gend - 1);
        const u16* krow = qkv + (size_t)knc*QKV_DIM + F_DIM + h*144;

        f32x16 sacc;
        #pragma unroll
        for (int e = 0; e < 16; e++) sacc[e] = 0.f;
        #pragma unroll
        for (int kk = 0; kk < 9; kk++){
            bf16x8 kf = *(const bf16x8*)(krow + kk*16 + hi*8);
            sacc = __builtin_amdgcn_mfma_f32_32x32x16_bf16(kf, qf[kk], sacc, 0, 0, 0);
        }

        float sarr[16];
        #pragma unroll
        for (int r = 0; r < 16; r++){
            float sv = sacc[r]*HD_SCALE + bf2f(braw[r]);
            sarr[r] = ((j0 + jlr[r]) < ng) ? sv : -INFINITY;
        }

        float rmax = -INFINITY;
        #pragma unroll
        for (int r = 0; r < 16; r++) rmax = fmaxf(rmax, sarr[r]);
        rmax = fmaxf(rmax, __shfl_xor(rmax, 32));

        if (!__all(rmax <= mrun + 5.0f)){     // T13 defer-rescale
            float mnew = fmaxf(mrun, rmax);
            float alpha = exp2f((mrun - mnew)*LOG2E);
            lrun *= alpha;
            float ar[16];
            #pragma unroll
            for (int r = 0; r < 16; r++) ar[r] = __shfl(alpha, jlr[r]);
            #pragma unroll
            for (int dt = 0; dt < 5; dt++)
                #pragma unroll
                for (int r = 0; r < 16; r++) O[dt][r] *= ar[r];
            mrun = mnew;
        }

        float psum = 0.f;
        #pragma unroll
        for (int r = 0; r < 16; r++){
            float p = exp2f((sarr[r] - mrun)*LOG2E);
            sarr[r] = p; psum += p;
        }
        psum += __shfl_xor(psum, 32);
        lrun += psum;

        // pack P -> bf16 A-fragment (halves exchange)
        u32 cpk[8], opk[8];
        #pragma unroll
        for (int q = 0; q < 8; q++) cpk[q] = pack2(sarr[2*q], sarr[2*q+1]);
        #pragma unroll
        for (int q = 0; q < 8; q++) opk[q] = (u32)__shfl_xor((int)cpk[q], 32);
        u32x4 a0, a1;
        if (hi == 0){
            a0[0]=cpk[0]; a0[1]=cpk[1]; a0[2]=opk[0]; a0[3]=opk[1];
            a1[0]=cpk[4]; a1[1]=cpk[5]; a1[2]=opk[4]; a1[3]=opk[5];
        } else {
            a0[0]=opk[2]; a0[1]=opk[3]; a0[2]=cpk[2]; a0[3]=cpk[3];
            a1[0]=opk[6]; a1[1]=opk[7]; a1[2]=cpk[6]; a1[3]=cpk[7];
        }
        bf16x8 paf[2];
        paf[0] = __builtin_bit_cast(bf16x8, a0);
        paf[1] = __builtin_bit_cast(bf16x8, a1);

        // PV: V fragments straight from VT (L2-resident per head/XCD)
        #pragma unroll
        for (int dt = 0; dt < 5; dt++){
            int d = dt*32 + li;
            int dc = (d > 143) ? 143 : d;
            const u16* vrow = VT + ((size_t)h*144 + dc)*PN + pst + j0;
            #pragma unroll
            for (int ks = 0; ks < 2; ks++){
                bf16x8 vf = *(const bf16x8*)(vrow + (ks*2 + hi)*8);
                O[dt] = __builtin_amdgcn_mfma_f32_32x32x16_bf16(paf[ks], vf, O[dt], 0, 0, 0);
            }
        }
    }

    // ---- cross-wave merge ----
    sml[0][w][li] = mrun;
    sml[1][w][li] = lrun;
    __syncthreads();
    if (tid < 32){
        int q = tid;
        float m0 = sml[0][0][q], m1 = sml[0][1][q];
        float m2 = sml[0][2][q], m3 = sml[0][3][q];
        float m = fmaxf(fmaxf(m0, m1), fmaxf(m2, m3));
        float f0 = exp2f((m0 - m)*LOG2E), f1 = exp2f((m1 - m)*LOG2E);
        float f2 = exp2f((m2 - m)*LOG2E), f3 = exp2f((m3 - m)*LOG2E);
        sfac[0][q] = f0; sfac[1][q] = f1; sfac[2][q] = f2; sfac[3][q] = f3;
        float L = f0*sml[1][0][q] + f1*sml[1][1][q] + f2*sml[1][2][q] + f3*sml[1][3][q];
        sLinv[q] = 1.0f / L;
    }
    __syncthreads();

    #pragma unroll 1
    for (int dt = 0; dt < 5; dt++){
        #pragma unroll
        for (int r = 0; r < 16; r++) sO[w][lane][r] = O[dt][r];
        __syncthreads();
        if (w == (dt & 3)){
            int d = dt*32 + li;
            if (d < 144){
                #pragma unroll
                for (int r = 0; r < 16; r++){
                    int q = jlr[r];
                    float s = sfac[0][q]*sO[0][lane][r] + sfac[1][q]*sO[1][lane][r]
                            + sfac[2][q]*sO[2][lane][r] + sfac[3][q]*sO[3][lane][r];
                    if (qt*32 + q < ng)
                        attn_out[(size_t)(qbase + q)*F_DIM + h*144 + d] = f2bf(s * sLinv[q]);
                }
            }
        }
        __syncthreads();
    }
}

// ---------------------------------------------------------------------------
// y = LayerNorm(x + out) * gamma + beta  (in-place over d_out)
// ---------------------------------------------------------------------------
__global__ __launch_bounds__(256) void ln_kernel(const float* __restrict__ x,
                                                 float* __restrict__ io,
                                                 const float* __restrict__ gamma,
                                                 const float* __restrict__ beta){
    const int node = blockIdx.x;
    const float* xr = x  + (size_t)node*F_DIM;
    float* yr       = io + (size_t)node*F_DIM;
    const int t = threadIdx.x;
    float h[5]; float s = 0.f, ss = 0.f;
    #pragma unroll
    for (int i = 0; i < 5; i++){
        int idx = t + i*256;
        float v = 0.f;
        if (idx < F_DIM) v = xr[idx] + yr[idx];
        h[i] = v; s += v; ss += v*v;
    }
    #pragma unroll
    for (int o = 32; o > 0; o >>= 1){ s += __shfl_down(s, o); ss += __shfl_down(ss, o); }
    __shared__ float rs[4], rss[4];
    __shared__ float smu, srstd;
    if ((t & 63) == 0){ rs[t>>6] = s; rss[t>>6] = ss; }
    __syncthreads();
    if (t == 0){
        float S  = rs[0]+rs[1]+rs[2]+rs[3];
        float SS = rss[0]+rss[1]+rss[2]+rss[3];
        float mu = S * (1.f/F_DIM);
        float var = SS * (1.f/F_DIM) - mu*mu;
        smu = mu; srstd = rsqrtf(var + 1e-5f);
    }
    __syncthreads();
    float mu = smu, rstd = srstd;
    #pragma unroll
    for (int i = 0; i < 5; i++){
        int idx = t + i*256;
        if (idx < F_DIM) yr[idx] = (h[i]-mu)*rstd*gamma[idx] + beta[idx];
    }
}

// ---------------------------------------------------------------------------
extern "C" void kernel_launch(void* const* d_in, const int* in_sizes, int n_in,
                              void* d_out, int out_size, void* d_ws, size_t ws_size,
                              hipStream_t stream){
    const float* x     = (const float*)d_in[0];
    const float* pos   = (const float*)d_in[1];
    const float* Wqkv  = (const float*)d_in[2];
    const float* Wout  = (const float*)d_in[3];
    const float* rfreq = (const float*)d_in[4];
    const float* Wrope = (const float*)d_in[5];
    const float* gamma = (const float*)d_in[6];
    const float* beta  = (const float*)d_in[7];
    const int*   batch = (const int*)d_in[8];

    const int N  = in_sizes[0] / F_DIM;     // 8192
    const int PN = N + 512;                 // padded V columns
    const int MAXT = N/32 + 16;             // 272

    char* ws = (char*)d_ws;
    size_t off = 0;
    auto alloc = [&](size_t b){ size_t o = off; off += (b + 255) & ~(size_t)255; return o; };
    int* meta   = (int*)(ws + alloc((size_t)(64 + 2*MAXT)*sizeof(int)));
    u16* xb     = (u16*)(ws + alloc((size_t)N*F_DIM*2));        // reused as attn_out
    u16* wqkvT  = (u16*)(ws + alloc((size_t)QKV_DIM*F_DIM*2));
    u16* woutT  = (u16*)(ws + alloc((size_t)F_DIM*F_DIM*2));
    u16* qkv    = (u16*)(ws + alloc((size_t)N*QKV_DIM*2));
    size_t vtBytes = (size_t)8*144*PN*2;
    u16* VT     = (u16*)(ws + alloc(vtBytes));
    u16* biasb  = (u16*)(ws + off);         // rest of workspace: bias blocks
    (void)ws_size; (void)n_in; (void)out_size;

    hipLaunchKernelGGL(setup_meta, dim3(1), dim3(64), 0, stream, batch, meta, N, MAXT);
    hipLaunchKernelGGL(cast_f32_bf16, dim3((N*F_DIM/4 + 255)/256), dim3(256), 0, stream,
                       x, xb, N*F_DIM/4);
    hipLaunchKernelGGL(transpose_cast, dim3(QKV_DIM/32, F_DIM/32), dim3(256), 0, stream,
                       Wqkv, wqkvT, F_DIM, QKV_DIM);
    hipLaunchKernelGGL(transpose_cast, dim3(F_DIM/32, F_DIM/32), dim3(256), 0, stream,
                       Wout, woutT, F_DIM, F_DIM);
    hipLaunchKernelGGL((gemm128<true>), dim3(N/128, QKV_DIM/128), dim3(256), 0, stream,
                       xb, wqkvT, (void*)qkv, N, QKV_DIM, F_DIM);
    hipMemsetAsync(VT, 0, vtBytes, stream);
    hipLaunchKernelGGL(build_vt, dim3(N/32, 5, 8), dim3(256), 0, stream,
                       qkv, VT, batch, meta, N, PN);
    hipLaunchKernelGGL(bias_kernel, dim3(2048), dim3(256), 0, stream,
                       pos, rfreq, Wrope, meta, biasb);
    hipLaunchKernelGGL(attn_kernel, dim3(MAXT*8), dim3(256), 0, stream,
                       qkv, VT, biasb, xb, meta, PN, MAXT);
    hipLaunchKernelGGL((gemm128<false>), dim3(N/128, F_DIM/128), dim3(256), 0, stream,
                       xb, woutT, d_out, N, F_DIM, F_DIM);
    hipLaunchKernelGGL(ln_kernel, dim3(N), dim3(256), 0, stream,
                       x, (float*)d_out, gamma, beta);
}

// Round 5
// 479.968 us; speedup vs baseline: 1.1050x; 1.1050x over previous
//
#include <hip/hip_runtime.h>

typedef unsigned short u16;
typedef unsigned int   u32;
typedef __attribute__((ext_vector_type(8)))  __bf16 bf16x8;
typedef __attribute__((ext_vector_type(4)))  float  f32x4;
typedef __attribute__((ext_vector_type(16))) float  f32x16;
typedef __attribute__((ext_vector_type(4)))  u32    u32x4;

#define F_DIM   1152
#define QKV_DIM 3456
#define HD_SCALE 0.083333333333333333f   // 1/sqrt(144)
#define LOG2E    1.4426950408889634f

static __device__ __forceinline__ u16 f2bf(float f){
    u32 u = __builtin_bit_cast(u32, f);
    u32 r = u + 0x7fffu + ((u >> 16) & 1u);   // RNE
    return (u16)(r >> 16);
}
static __device__ __forceinline__ float bf2f(u16 h){
    u32 u = ((u32)h) << 16;
    return __builtin_bit_cast(float, u);
}
static __device__ __forceinline__ u32 pack2(float a, float b){
    return (u32)f2bf(a) | ((u32)f2bf(b) << 16);
}

typedef __attribute__((address_space(1))) void gvoid;
typedef __attribute__((address_space(3))) void lvoid;
static __device__ __forceinline__ void gload16(const u16* g, u16* l){
    __builtin_amdgcn_global_load_lds((gvoid*)g, (lvoid*)l, 16, 0, 0);
}

// ---------------------------------------------------------------------------
// meta: [0]=ntiles  [1..17]=graph offsets  [20..36]=padded V col starts
//       [40..56]=bias block offsets  [64+i]=tile graph  [64+MAXT+i]=tile q idx
// ---------------------------------------------------------------------------
__global__ void setup_meta(const int* __restrict__ batch, int* __restrict__ meta,
                           int N, int maxTiles){
    int t = threadIdx.x;
    if (t <= 16){
        int lo = 0, hi = N;
        while (lo < hi){ int mid = (lo+hi)>>1; if (batch[mid] < t) lo = mid+1; else hi = mid; }
        meta[1+t] = lo;
    }
    __syncthreads();
    if (t == 0){
        int cnt = 0, ps = 0, bcnt = 0;
        for (int g = 0; g < 16; g++){
            int ng = meta[2+g] - meta[1+g];
            meta[20+g] = ps;
            meta[40+g] = bcnt;
            int nt = (ng + 31) / 32;
            ps += nt * 32;
            bcnt += nt * nt;
            for (int q = 0; q < nt; q++){
                meta[64 + cnt] = g;
                meta[64 + maxTiles + cnt] = q;
                cnt++;
            }
        }
        meta[36] = ps;
        meta[56] = bcnt;
        meta[0]  = cnt;
    }
}

__global__ __launch_bounds__(256) void cast_f32_bf16(const float* __restrict__ in,
                                                     u16* __restrict__ out, int n4){
    int i = blockIdx.x*256 + threadIdx.x;
    if (i < n4){
        float4 v = ((const float4*)in)[i];
        ((ushort4*)out)[i] = make_ushort4(f2bf(v.x), f2bf(v.y), f2bf(v.z), f2bf(v.w));
    }
}

__global__ __launch_bounds__(256) void transpose_cast(const float* __restrict__ in,
                                                      u16* __restrict__ out, int R, int C){
    __shared__ float tile[32][33];
    int c0 = blockIdx.x*32, r0 = blockIdx.y*32;
    int tx = threadIdx.x & 31, ty = threadIdx.x >> 5;
    #pragma unroll
    for (int yy = ty; yy < 32; yy += 8){
        int r = r0+yy, c = c0+tx;
        tile[yy][tx] = (r < R && c < C) ? in[(size_t)r*C + c] : 0.f;
    }
    __syncthreads();
    #pragma unroll
    for (int yy = ty; yy < 32; yy += 8){
        int oc = c0+yy, orr = r0+tx;
        if (oc < C && orr < R) out[(size_t)oc*R + orr] = f2bf(tile[tx][yy]);
    }
}

// ---------------------------------------------------------------------------
// C[M,Ncols] = A[M,K] * Bt[Ncols,K]^T ; 128x128 tile, BK=32, global_load_lds,
// XCD-aware bijective swizzle.
// ---------------------------------------------------------------------------
template<bool OUT_BF16>
__global__ __launch_bounds__(256) void gemm128(const u16* __restrict__ A,
                                               const u16* __restrict__ Bt,
                                               void* __restrict__ Cp,
                                               int M, int Ncols, int K){
    __shared__ u16 sA[128*32];
    __shared__ u16 sB[128*32];
    const int nwg = gridDim.x * gridDim.y;
    int orig = blockIdx.y * gridDim.x + blockIdx.x;
    int qq = nwg >> 3, rr = nwg & 7;
    int xcd = orig & 7, pos = orig >> 3;
    int nid = (xcd < rr ? xcd*(qq+1) : rr*(qq+1) + (xcd-rr)*qq) + pos;
    const int bm = (nid % gridDim.x) * 128, bn = (nid / gridDim.x) * 128;

    const int t = threadIdx.x;
    const int lane = t & 63, w = t >> 6;
    const int wr = w >> 1, wc = w & 1;
    const int fr = lane & 15, fq = lane >> 4;

    f32x16 accf[4];
    #pragma unroll
    for (int m = 0; m < 4; m++)
        #pragma unroll
        for (int e = 0; e < 16; e++) accf[m][e] = 0.f;

    const u16* aptr = A  + (size_t)(bm + (t>>2))*K + ((t&3)<<3);
    const u16* bptr = Bt + (size_t)(bn + (t>>2))*K + ((t&3)<<3);
    const size_t half = (size_t)64*K;

    for (int k0 = 0; k0 < K; k0 += 32){
        __syncthreads();
        gload16(aptr + k0,        &sA[t*8]);
        gload16(aptr + k0 + half, &sA[2048 + t*8]);
        gload16(bptr + k0,        &sB[t*8]);
        gload16(bptr + k0 + half, &sB[2048 + t*8]);
        __syncthreads();
        bf16x8 af[4], bfr[4];
        #pragma unroll
        for (int m = 0; m < 4; m++) af[m]  = *(const bf16x8*)(&sA[(wr*64 + m*16 + fr)*32 + fq*8]);
        #pragma unroll
        for (int n = 0; n < 4; n++) bfr[n] = *(const bf16x8*)(&sB[(wc*64 + n*16 + fr)*32 + fq*8]);
        #pragma unroll
        for (int m = 0; m < 4; m++){
            #pragma unroll
            for (int n = 0; n < 4; n++){
                f32x4 a; a[0]=accf[m][n*4+0]; a[1]=accf[m][n*4+1]; a[2]=accf[m][n*4+2]; a[3]=accf[m][n*4+3];
                a = __builtin_amdgcn_mfma_f32_16x16x32_bf16(af[m], bfr[n], a, 0, 0, 0);
                accf[m][n*4+0]=a[0]; accf[m][n*4+1]=a[1]; accf[m][n*4+2]=a[2]; accf[m][n*4+3]=a[3];
            }
        }
    }
    #pragma unroll
    for (int m = 0; m < 4; m++)
        #pragma unroll
        for (int n = 0; n < 4; n++)
            #pragma unroll
            for (int r = 0; r < 4; r++){
                int row = bm + wr*64 + m*16 + fq*4 + r;
                int col = bn + wc*64 + n*16 + fr;
                float v = accf[m][n*4+r];
                if (OUT_BF16) ((u16*)Cp)[(size_t)row*Ncols + col] = f2bf(v);
                else          ((float*)Cp)[(size_t)row*Ncols + col] = v;
            }
}

// ---------------------------------------------------------------------------
// VT[h][d][pcol] = v[node][h*144+d]
// ---------------------------------------------------------------------------
__global__ __launch_bounds__(256) void build_vt(const u16* __restrict__ qkv,
                                                u16* __restrict__ VT,
                                                const int* __restrict__ batch,
                                                const int* __restrict__ meta,
                                                int N, int PN){
    __shared__ u16 tile[32][33];
    int nt0 = blockIdx.x*32, dt0 = blockIdx.y*32, h = blockIdx.z;
    int tx = threadIdx.x & 31, ty = threadIdx.x >> 5;
    #pragma unroll
    for (int yy = ty; yy < 32; yy += 8){
        int node = nt0+yy, d = dt0+tx;
        tile[yy][tx] = (d < 144) ? qkv[(size_t)node*QKV_DIM + 2*F_DIM + h*144 + d] : (u16)0;
    }
    __syncthreads();
    int node = nt0 + tx;
    int g = batch[node];
    int col = meta[20+g] + (node - meta[1+g]);
    #pragma unroll
    for (int yy = ty; yy < 32; yy += 8){
        int d = dt0+yy;
        if (d < 144) VT[((size_t)h*144 + d)*PN + col] = tile[tx][yy];
    }
}

// ---------------------------------------------------------------------------
// Fourier bias precompute, cos shared across heads.
// bias[block(g,qt,jt)*8192 + h*1024 + j*32 + i]  (bf16)
// ---------------------------------------------------------------------------
__global__ __launch_bounds__(256) void bias_kernel(const float* __restrict__ pos,
                                                   const float* __restrict__ rfreq,
                                                   const float* __restrict__ Wrope,
                                                   const int* __restrict__ meta,
                                                   u16* __restrict__ bias){
    float absf[16], w[16][8];
    #pragma unroll
    for (int r = 0; r < 16; r++){
        absf[r] = fabsf(rfreq[r]);
        #pragma unroll
        for (int h = 0; h < 8; h++) w[r][h] = Wrope[r*8 + h];
    }
    const int total = meta[56];
    const int t = threadIdx.x;
    for (int bb = blockIdx.x; bb < total; bb += gridDim.x){
        int g = 0;
        while (meta[40 + g + 1] <= bb) g++;
        int rem  = bb - meta[40 + g];
        int goff = meta[1+g];
        int ng   = meta[2+g] - goff;
        int ntg  = (ng + 31) >> 5;
        int qt   = rem / ntg;
        int jt   = rem - qt*ntg;
        size_t base = (size_t)bb * 8192;
        #pragma unroll
        for (int pp = 0; pp < 4; pp++){
            int p = t + pp*256;
            int qn = goff + qt*32 + (p & 31);  if (qn >= goff + ng) qn = goff + ng - 1;
            int kn = goff + jt*32 + (p >> 5);  if (kn >= goff + ng) kn = goff + ng - 1;
            float dx = pos[qn*3+0] - pos[kn*3+0];
            float dy = pos[qn*3+1] - pos[kn*3+1];
            float dz = pos[qn*3+2] - pos[kn*3+2];
            float d  = sqrtf(dx*dx + dy*dy + dz*dz);
            float b[8];
            #pragma unroll
            for (int h = 0; h < 8; h++) b[h] = 0.f;
            #pragma unroll
            for (int r = 0; r < 16; r++){
                float c = __cosf(d * absf[r]);
                #pragma unroll
                for (int h = 0; h < 8; h++) b[h] = fmaf(c, w[r][h], b[h]);
            }
            #pragma unroll
            for (int h = 0; h < 8; h++)
                bias[base + h*1024 + p] = f2bf(b[h]);
        }
    }
}

// ---------------------------------------------------------------------------
// Flash attention, split-KV x4: one block = (q-tile, head), 4 waves.
// Wave w processes KV tiles t = w, w+4, ... independently (K/V from L2),
// then the 4 partials (m,l,O) merge through LDS. Grid is 1-D MAXT*8 with
// XCD-chunked decode: XCD x <-> head x (per-XCD L2 holds one head's K/V).
// NOTE: merge dt-loop MUST be fully unrolled -- runtime-indexing O[dt]
// demotes the accumulator to scratch (rule #20; round-4 regression).
// ---------------------------------------------------------------------------
__global__ __launch_bounds__(256) void attn_kernel(
        const u16* __restrict__ qkv, const u16* __restrict__ VT,
        const u16* __restrict__ bias, u16* __restrict__ attn_out,
        const int* __restrict__ meta, int PN, int MAXT){
    __shared__ float sml[2][4][32];
    __shared__ float sfac[4][32];
    __shared__ float sLinv[32];
    __shared__ float sO[4][64][17];    // +1 pad: conflict-free merge

    // XCD-chunked bijective decode (gridDim.x = MAXT*8, divisible by 8)
    const int q8 = gridDim.x >> 3;
    const int work = ((int)blockIdx.x & 7)*q8 + ((int)blockIdx.x >> 3);
    const int h = work / MAXT;
    const int tile = work - h*MAXT;
    if (tile >= meta[0]) return;

    const int g    = meta[64 + tile];
    const int qt   = meta[64 + MAXT + tile];
    const int goff = meta[1+g], gend = meta[2+g];
    const int ng   = gend - goff;
    const int ntg  = (ng + 31) >> 5;
    const int qbase = goff + qt*32;
    const int pst  = meta[20+g];
    const int boffg= meta[40+g];

    const int tid = threadIdx.x;
    const int w = tid >> 6, lane = tid & 63;
    const int li = lane & 31, hi = lane >> 5;

    int qnode = qbase + li; if (qnode >= gend) qnode = gend - 1;
    const u16* qrow = qkv + (size_t)qnode*QKV_DIM + h*144;
    bf16x8 qf[9];
    #pragma unroll
    for (int kk = 0; kk < 9; kk++) qf[kk] = *(const bf16x8*)(qrow + kk*16 + hi*8);

    int jlr[16];
    #pragma unroll
    for (int r = 0; r < 16; r++) jlr[r] = (r & 3) + ((r >> 2) << 3) + (hi << 2);

    const u16* bbase = bias + ((size_t)boffg + (size_t)qt*ntg)*8192 + h*1024 + li;

    float mrun = -INFINITY, lrun = 0.f;
    f32x16 O[5];
    #pragma unroll
    for (int dt = 0; dt < 5; dt++)
        #pragma unroll
        for (int e = 0; e < 16; e++) O[dt][e] = 0.f;

    #pragma unroll 1
    for (int t = w; t < ntg; t += 4){
        const int j0 = t*32;
        // bias loads issued early, consumed after QK chain
        const u16* bt = bbase + (size_t)t*8192;
        u16 braw[16];
        #pragma unroll
        for (int r = 0; r < 16; r++) braw[r] = bt[jlr[r]*32];

        int knc = ((j0 + li) < ng) ? (goff + j0 + li) : (gend - 1);
        const u16* krow = qkv + (size_t)knc*QKV_DIM + F_DIM + h*144;

        f32x16 sacc;
        #pragma unroll
        for (int e = 0; e < 16; e++) sacc[e] = 0.f;
        #pragma unroll
        for (int kk = 0; kk < 9; kk++){
            bf16x8 kf = *(const bf16x8*)(krow + kk*16 + hi*8);
            sacc = __builtin_amdgcn_mfma_f32_32x32x16_bf16(kf, qf[kk], sacc, 0, 0, 0);
        }

        float sarr[16];
        #pragma unroll
        for (int r = 0; r < 16; r++){
            float sv = sacc[r]*HD_SCALE + bf2f(braw[r]);
            sarr[r] = ((j0 + jlr[r]) < ng) ? sv : -INFINITY;
        }

        float rmax = -INFINITY;
        #pragma unroll
        for (int r = 0; r < 16; r++) rmax = fmaxf(rmax, sarr[r]);
        rmax = fmaxf(rmax, __shfl_xor(rmax, 32));

        if (!__all(rmax <= mrun + 5.0f)){     // T13 defer-rescale
            float mnew = fmaxf(mrun, rmax);
            float alpha = exp2f((mrun - mnew)*LOG2E);
            lrun *= alpha;
            float ar[16];
            #pragma unroll
            for (int r = 0; r < 16; r++) ar[r] = __shfl(alpha, jlr[r]);
            #pragma unroll
            for (int dt = 0; dt < 5; dt++)
                #pragma unroll
                for (int r = 0; r < 16; r++) O[dt][r] *= ar[r];
            mrun = mnew;
        }

        float psum = 0.f;
        #pragma unroll
        for (int r = 0; r < 16; r++){
            float p = exp2f((sarr[r] - mrun)*LOG2E);
            sarr[r] = p; psum += p;
        }
        psum += __shfl_xor(psum, 32);
        lrun += psum;

        // pack P -> bf16 A-fragment (halves exchange)
        u32 cpk[8], opk[8];
        #pragma unroll
        for (int q = 0; q < 8; q++) cpk[q] = pack2(sarr[2*q], sarr[2*q+1]);
        #pragma unroll
        for (int q = 0; q < 8; q++) opk[q] = (u32)__shfl_xor((int)cpk[q], 32);
        u32x4 a0, a1;
        if (hi == 0){
            a0[0]=cpk[0]; a0[1]=cpk[1]; a0[2]=opk[0]; a0[3]=opk[1];
            a1[0]=cpk[4]; a1[1]=cpk[5]; a1[2]=opk[4]; a1[3]=opk[5];
        } else {
            a0[0]=opk[2]; a0[1]=opk[3]; a0[2]=cpk[2]; a0[3]=cpk[3];
            a1[0]=opk[6]; a1[1]=opk[7]; a1[2]=cpk[6]; a1[3]=cpk[7];
        }
        bf16x8 paf[2];
        paf[0] = __builtin_bit_cast(bf16x8, a0);
        paf[1] = __builtin_bit_cast(bf16x8, a1);

        // PV: V fragments straight from VT (L2-resident per head/XCD)
        #pragma unroll
        for (int dt = 0; dt < 5; dt++){
            int d = dt*32 + li;
            int dc = (d > 143) ? 143 : d;
            const u16* vrow = VT + ((size_t)h*144 + dc)*PN + pst + j0;
            #pragma unroll
            for (int ks = 0; ks < 2; ks++){
                bf16x8 vf = *(const bf16x8*)(vrow + (ks*2 + hi)*8);
                O[dt] = __builtin_amdgcn_mfma_f32_32x32x16_bf16(paf[ks], vf, O[dt], 0, 0, 0);
            }
        }
    }

    // ---- cross-wave merge ----
    sml[0][w][li] = mrun;
    sml[1][w][li] = lrun;
    __syncthreads();
    if (tid < 32){
        int q = tid;
        float m0 = sml[0][0][q], m1 = sml[0][1][q];
        float m2 = sml[0][2][q], m3 = sml[0][3][q];
        float m = fmaxf(fmaxf(m0, m1), fmaxf(m2, m3));
        float f0 = exp2f((m0 - m)*LOG2E), f1 = exp2f((m1 - m)*LOG2E);
        float f2 = exp2f((m2 - m)*LOG2E), f3 = exp2f((m3 - m)*LOG2E);
        sfac[0][q] = f0; sfac[1][q] = f1; sfac[2][q] = f2; sfac[3][q] = f3;
        float L = f0*sml[1][0][q] + f1*sml[1][1][q] + f2*sml[1][2][q] + f3*sml[1][3][q];
        sLinv[q] = 1.0f / L;
    }
    __syncthreads();

    #pragma unroll              // MUST stay fully unrolled: O[dt] static index
    for (int dt = 0; dt < 5; dt++){
        #pragma unroll
        for (int r = 0; r < 16; r++) sO[w][lane][r] = O[dt][r];
        __syncthreads();
        if (w == (dt & 3)){
            int d = dt*32 + li;
            if (d < 144){
                #pragma unroll
                for (int r = 0; r < 16; r++){
                    int q = jlr[r];
                    float s = sfac[0][q]*sO[0][lane][r] + sfac[1][q]*sO[1][lane][r]
                            + sfac[2][q]*sO[2][lane][r] + sfac[3][q]*sO[3][lane][r];
                    if (qt*32 + q < ng)
                        attn_out[(size_t)(qbase + q)*F_DIM + h*144 + d] = f2bf(s * sLinv[q]);
                }
            }
        }
        __syncthreads();
    }
}

// ---------------------------------------------------------------------------
// y = LayerNorm(x + out) * gamma + beta  (in-place over d_out)
// ---------------------------------------------------------------------------
__global__ __launch_bounds__(256) void ln_kernel(const float* __restrict__ x,
                                                 float* __restrict__ io,
                                                 const float* __restrict__ gamma,
                                                 const float* __restrict__ beta){
    const int node = blockIdx.x;
    const float* xr = x  + (size_t)node*F_DIM;
    float* yr       = io + (size_t)node*F_DIM;
    const int t = threadIdx.x;
    float h[5]; float s = 0.f, ss = 0.f;
    #pragma unroll
    for (int i = 0; i < 5; i++){
        int idx = t + i*256;
        float v = 0.f;
        if (idx < F_DIM) v = xr[idx] + yr[idx];
        h[i] = v; s += v; ss += v*v;
    }
    #pragma unroll
    for (int o = 32; o > 0; o >>= 1){ s += __shfl_down(s, o); ss += __shfl_down(ss, o); }
    __shared__ float rs[4], rss[4];
    __shared__ float smu, srstd;
    if ((t & 63) == 0){ rs[t>>6] = s; rss[t>>6] = ss; }
    __syncthreads();
    if (t == 0){
        float S  = rs[0]+rs[1]+rs[2]+rs[3];
        float SS = rss[0]+rss[1]+rss[2]+rss[3];
        float mu = S * (1.f/F_DIM);
        float var = SS * (1.f/F_DIM) - mu*mu;
        smu = mu; srstd = rsqrtf(var + 1e-5f);
    }
    __syncthreads();
    float mu = smu, rstd = srstd;
    #pragma unroll
    for (int i = 0; i < 5; i++){
        int idx = t + i*256;
        if (idx < F_DIM) yr[idx] = (h[i]-mu)*rstd*gamma[idx] + beta[idx];
    }
}

// ---------------------------------------------------------------------------
extern "C" void kernel_launch(void* const* d_in, const int* in_sizes, int n_in,
                              void* d_out, int out_size, void* d_ws, size_t ws_size,
                              hipStream_t stream){
    const float* x     = (const float*)d_in[0];
    const float* pos   = (const float*)d_in[1];
    const float* Wqkv  = (const float*)d_in[2];
    const float* Wout  = (const float*)d_in[3];
    const float* rfreq = (const float*)d_in[4];
    const float* Wrope = (const float*)d_in[5];
    const float* gamma = (const float*)d_in[6];
    const float* beta  = (const float*)d_in[7];
    const int*   batch = (const int*)d_in[8];

    const int N  = in_sizes[0] / F_DIM;     // 8192
    const int PN = N + 512;                 // padded V columns
    const int MAXT = N/32 + 16;             // 272

    char* ws = (char*)d_ws;
    size_t off = 0;
    auto alloc = [&](size_t b){ size_t o = off; off += (b + 255) & ~(size_t)255; return o; };
    int* meta   = (int*)(ws + alloc((size_t)(64 + 2*MAXT)*sizeof(int)));
    u16* xb     = (u16*)(ws + alloc((size_t)N*F_DIM*2));        // reused as attn_out
    u16* wqkvT  = (u16*)(ws + alloc((size_t)QKV_DIM*F_DIM*2));
    u16* woutT  = (u16*)(ws + alloc((size_t)F_DIM*F_DIM*2));
    u16* qkv    = (u16*)(ws + alloc((size_t)N*QKV_DIM*2));
    size_t vtBytes = (size_t)8*144*PN*2;
    u16* VT     = (u16*)(ws + alloc(vtBytes));
    u16* biasb  = (u16*)(ws + off);         // rest of workspace: bias blocks
    (void)ws_size; (void)n_in; (void)out_size;

    hipLaunchKernelGGL(setup_meta, dim3(1), dim3(64), 0, stream, batch, meta, N, MAXT);
    hipLaunchKernelGGL(cast_f32_bf16, dim3((N*F_DIM/4 + 255)/256), dim3(256), 0, stream,
                       x, xb, N*F_DIM/4);
    hipLaunchKernelGGL(transpose_cast, dim3(QKV_DIM/32, F_DIM/32), dim3(256), 0, stream,
                       Wqkv, wqkvT, F_DIM, QKV_DIM);
    hipLaunchKernelGGL(transpose_cast, dim3(F_DIM/32, F_DIM/32), dim3(256), 0, stream,
                       Wout, woutT, F_DIM, F_DIM);
    hipLaunchKernelGGL((gemm128<true>), dim3(N/128, QKV_DIM/128), dim3(256), 0, stream,
                       xb, wqkvT, (void*)qkv, N, QKV_DIM, F_DIM);
    hipMemsetAsync(VT, 0, vtBytes, stream);
    hipLaunchKernelGGL(build_vt, dim3(N/32, 5, 8), dim3(256), 0, stream,
                       qkv, VT, batch, meta, N, PN);
    hipLaunchKernelGGL(bias_kernel, dim3(2048), dim3(256), 0, stream,
                       pos, rfreq, Wrope, meta, biasb);
    hipLaunchKernelGGL(attn_kernel, dim3(MAXT*8), dim3(256), 0, stream,
                       qkv, VT, biasb, xb, meta, PN, MAXT);
    hipLaunchKernelGGL((gemm128<false>), dim3(N/128, F_DIM/128), dim3(256), 0, stream,
                       xb, woutT, d_out, N, F_DIM, F_DIM);
    hipLaunchKernelGGL(ln_kernel, dim3(N), dim3(256), 0, stream,
                       x, (float*)d_out, gamma, beta);
}

// Round 6
// 468.768 us; speedup vs baseline: 1.1314x; 1.0239x over previous
//
#include <hip/hip_runtime.h>

typedef unsigned short u16;
typedef unsigned int   u32;
typedef __attribute__((ext_vector_type(8)))  __bf16 bf16x8;
typedef __attribute__((ext_vector_type(4)))  float  f32x4;
typedef __attribute__((ext_vector_type(16))) float  f32x16;
typedef __attribute__((ext_vector_type(4)))  u32    u32x4;

#define F_DIM   1152
#define QKV_DIM 3456
#define HD_SCALE 0.083333333333333333f   // 1/sqrt(144)
#define LOG2E    1.4426950408889634f

static __device__ __forceinline__ u16 f2bf(float f){
    u32 u = __builtin_bit_cast(u32, f);
    u32 r = u + 0x7fffu + ((u >> 16) & 1u);   // RNE
    return (u16)(r >> 16);
}
static __device__ __forceinline__ float bf2f(u16 h){
    u32 u = ((u32)h) << 16;
    return __builtin_bit_cast(float, u);
}
static __device__ __forceinline__ u32 pack2(float a, float b){
    return (u32)f2bf(a) | ((u32)f2bf(b) << 16);
}

typedef __attribute__((address_space(1))) void gvoid;
typedef __attribute__((address_space(3))) void lvoid;
static __device__ __forceinline__ void gload16(const u16* g, u16* l){
    __builtin_amdgcn_global_load_lds((gvoid*)g, (lvoid*)l, 16, 0, 0);
}

// ---------------------------------------------------------------------------
// meta: [0]=ntiles  [1..17]=graph offsets  [20..36]=padded V col starts
//       [40..56]=bias block offsets  [64+i]=tile graph  [64+MAXT+i]=tile q idx
// ---------------------------------------------------------------------------
__global__ void setup_meta(const int* __restrict__ batch, int* __restrict__ meta,
                           int N, int maxTiles){
    int t = threadIdx.x;
    if (t <= 16){
        int lo = 0, hi = N;
        while (lo < hi){ int mid = (lo+hi)>>1; if (batch[mid] < t) lo = mid+1; else hi = mid; }
        meta[1+t] = lo;
    }
    __syncthreads();
    if (t == 0){
        int cnt = 0, ps = 0, bcnt = 0;
        for (int g = 0; g < 16; g++){
            int ng = meta[2+g] - meta[1+g];
            meta[20+g] = ps;
            meta[40+g] = bcnt;
            int nt = (ng + 31) / 32;
            ps += nt * 32;
            bcnt += nt * nt;
            for (int q = 0; q < nt; q++){
                meta[64 + cnt] = g;
                meta[64 + maxTiles + cnt] = q;
                cnt++;
            }
        }
        meta[36] = ps;
        meta[56] = bcnt;
        meta[0]  = cnt;
    }
}

__global__ __launch_bounds__(256) void cast_f32_bf16(const float* __restrict__ in,
                                                     u16* __restrict__ out, int n4){
    int i = blockIdx.x*256 + threadIdx.x;
    if (i < n4){
        float4 v = ((const float4*)in)[i];
        ((ushort4*)out)[i] = make_ushort4(f2bf(v.x), f2bf(v.y), f2bf(v.z), f2bf(v.w));
    }
}

__global__ __launch_bounds__(256) void transpose_cast(const float* __restrict__ in,
                                                      u16* __restrict__ out, int R, int C){
    __shared__ float tile[32][33];
    int c0 = blockIdx.x*32, r0 = blockIdx.y*32;
    int tx = threadIdx.x & 31, ty = threadIdx.x >> 5;
    #pragma unroll
    for (int yy = ty; yy < 32; yy += 8){
        int r = r0+yy, c = c0+tx;
        tile[yy][tx] = (r < R && c < C) ? in[(size_t)r*C + c] : 0.f;
    }
    __syncthreads();
    #pragma unroll
    for (int yy = ty; yy < 32; yy += 8){
        int oc = c0+yy, orr = r0+tx;
        if (oc < C && orr < R) out[(size_t)oc*R + orr] = f2bf(tile[tx][yy]);
    }
}

// ---------------------------------------------------------------------------
// C[M,Ncols] = A[M,K] * Bt[Ncols,K]^T ; 128x128 tile, BK=32, global_load_lds,
// XCD-aware bijective swizzle.
// ---------------------------------------------------------------------------
template<bool OUT_BF16>
__global__ __launch_bounds__(256) void gemm128(const u16* __restrict__ A,
                                               const u16* __restrict__ Bt,
                                               void* __restrict__ Cp,
                                               int M, int Ncols, int K){
    __shared__ u16 sA[128*32];
    __shared__ u16 sB[128*32];
    const int nwg = gridDim.x * gridDim.y;
    int orig = blockIdx.y * gridDim.x + blockIdx.x;
    int qq = nwg >> 3, rr = nwg & 7;
    int xcd = orig & 7, pos = orig >> 3;
    int nid = (xcd < rr ? xcd*(qq+1) : rr*(qq+1) + (xcd-rr)*qq) + pos;
    const int bm = (nid % gridDim.x) * 128, bn = (nid / gridDim.x) * 128;

    const int t = threadIdx.x;
    const int lane = t & 63, w = t >> 6;
    const int wr = w >> 1, wc = w & 1;
    const int fr = lane & 15, fq = lane >> 4;

    f32x16 accf[4];
    #pragma unroll
    for (int m = 0; m < 4; m++)
        #pragma unroll
        for (int e = 0; e < 16; e++) accf[m][e] = 0.f;

    const u16* aptr = A  + (size_t)(bm + (t>>2))*K + ((t&3)<<3);
    const u16* bptr = Bt + (size_t)(bn + (t>>2))*K + ((t&3)<<3);
    const size_t half = (size_t)64*K;

    for (int k0 = 0; k0 < K; k0 += 32){
        __syncthreads();
        gload16(aptr + k0,        &sA[t*8]);
        gload16(aptr + k0 + half, &sA[2048 + t*8]);
        gload16(bptr + k0,        &sB[t*8]);
        gload16(bptr + k0 + half, &sB[2048 + t*8]);
        __syncthreads();
        bf16x8 af[4], bfr[4];
        #pragma unroll
        for (int m = 0; m < 4; m++) af[m]  = *(const bf16x8*)(&sA[(wr*64 + m*16 + fr)*32 + fq*8]);
        #pragma unroll
        for (int n = 0; n < 4; n++) bfr[n] = *(const bf16x8*)(&sB[(wc*64 + n*16 + fr)*32 + fq*8]);
        #pragma unroll
        for (int m = 0; m < 4; m++){
            #pragma unroll
            for (int n = 0; n < 4; n++){
                f32x4 a; a[0]=accf[m][n*4+0]; a[1]=accf[m][n*4+1]; a[2]=accf[m][n*4+2]; a[3]=accf[m][n*4+3];
                a = __builtin_amdgcn_mfma_f32_16x16x32_bf16(af[m], bfr[n], a, 0, 0, 0);
                accf[m][n*4+0]=a[0]; accf[m][n*4+1]=a[1]; accf[m][n*4+2]=a[2]; accf[m][n*4+3]=a[3];
            }
        }
    }
    #pragma unroll
    for (int m = 0; m < 4; m++)
        #pragma unroll
        for (int n = 0; n < 4; n++)
            #pragma unroll
            for (int r = 0; r < 4; r++){
                int row = bm + wr*64 + m*16 + fq*4 + r;
                int col = bn + wc*64 + n*16 + fr;
                float v = accf[m][n*4+r];
                if (OUT_BF16) ((u16*)Cp)[(size_t)row*Ncols + col] = f2bf(v);
                else          ((float*)Cp)[(size_t)row*Ncols + col] = v;
            }
}

// ---------------------------------------------------------------------------
// Kpack[h][pcol][144] = k[node][h*144+d] ; dense 288B rows per padded column.
// ---------------------------------------------------------------------------
__global__ __launch_bounds__(256) void pack_k(const u16* __restrict__ qkv,
                                              u16* __restrict__ Kpack,
                                              const int* __restrict__ batch,
                                              const int* __restrict__ meta,
                                              int PN){
    const int nt0 = blockIdx.x*32, h = blockIdx.y;
    const int tid = threadIdx.x;
    #pragma unroll
    for (int i = tid; i < 576; i += 256){        // 32 nodes x 18 chunks(16B)
        int nl = i / 18, c = i - nl*18;
        int node = nt0 + nl;
        int g = batch[node];
        int col = meta[20+g] + (node - meta[1+g]);
        const u16* src = qkv + (size_t)node*QKV_DIM + F_DIM + h*144 + c*8;
        u16* dst = Kpack + ((size_t)h*PN + col)*144 + c*8;
        *(u32x4*)dst = *(const u32x4*)src;
    }
}

// ---------------------------------------------------------------------------
// Vpack[h][ptile][d=144][key&31] = v[node][h*144+d] ; dense 9KB per KV tile.
// ---------------------------------------------------------------------------
__global__ __launch_bounds__(256) void pack_v(const u16* __restrict__ qkv,
                                              u16* __restrict__ Vpack,
                                              const int* __restrict__ batch,
                                              const int* __restrict__ meta,
                                              int PT){
    __shared__ u16 tile[32][33];
    int nt0 = blockIdx.x*32, dt0 = blockIdx.y*32, h = blockIdx.z;
    int tx = threadIdx.x & 31, ty = threadIdx.x >> 5;
    #pragma unroll
    for (int yy = ty; yy < 32; yy += 8){
        int node = nt0+yy, d = dt0+tx;
        tile[yy][tx] = (d < 144) ? qkv[(size_t)node*QKV_DIM + 2*F_DIM + h*144 + d] : (u16)0;
    }
    __syncthreads();
    int node = nt0 + tx;
    int g = batch[node];
    int col = meta[20+g] + (node - meta[1+g]);
    int pt = col >> 5, cl = col & 31;
    #pragma unroll
    for (int yy = ty; yy < 32; yy += 8){
        int d = dt0+yy;
        if (d < 144) Vpack[(((size_t)h*PT + pt)*144 + d)*32 + cl] = tile[tx][yy];
    }
}

// ---------------------------------------------------------------------------
// Fourier bias precompute, cos shared across heads.
// bias[block(g,qt,jt)*8192 + h*1024 + j*32 + i]  (bf16)
// ---------------------------------------------------------------------------
__global__ __launch_bounds__(256) void bias_kernel(const float* __restrict__ pos,
                                                   const float* __restrict__ rfreq,
                                                   const float* __restrict__ Wrope,
                                                   const int* __restrict__ meta,
                                                   u16* __restrict__ bias){
    float absf[16], w[16][8];
    #pragma unroll
    for (int r = 0; r < 16; r++){
        absf[r] = fabsf(rfreq[r]);
        #pragma unroll
        for (int h = 0; h < 8; h++) w[r][h] = Wrope[r*8 + h];
    }
    const int total = meta[56];
    const int t = threadIdx.x;
    for (int bb = blockIdx.x; bb < total; bb += gridDim.x){
        int g = 0;
        while (meta[40 + g + 1] <= bb) g++;
        int rem  = bb - meta[40 + g];
        int goff = meta[1+g];
        int ng   = meta[2+g] - goff;
        int ntg  = (ng + 31) >> 5;
        int qt   = rem / ntg;
        int jt   = rem - qt*ntg;
        size_t base = (size_t)bb * 8192;
        #pragma unroll
        for (int pp = 0; pp < 4; pp++){
            int p = t + pp*256;
            int qn = goff + qt*32 + (p & 31);  if (qn >= goff + ng) qn = goff + ng - 1;
            int kn = goff + jt*32 + (p >> 5);  if (kn >= goff + ng) kn = goff + ng - 1;
            float dx = pos[qn*3+0] - pos[kn*3+0];
            float dy = pos[qn*3+1] - pos[kn*3+1];
            float dz = pos[qn*3+2] - pos[kn*3+2];
            float d  = sqrtf(dx*dx + dy*dy + dz*dz);
            float b[8];
            #pragma unroll
            for (int h = 0; h < 8; h++) b[h] = 0.f;
            #pragma unroll
            for (int r = 0; r < 16; r++){
                float c = __cosf(d * absf[r]);
                #pragma unroll
                for (int h = 0; h < 8; h++) b[h] = fmaf(c, w[r][h], b[h]);
            }
            #pragma unroll
            for (int h = 0; h < 8; h++)
                bias[base + h*1024 + p] = f2bf(b[h]);
        }
    }
}

// ---------------------------------------------------------------------------
// Flash attention, split-KV x4: one block = (q-tile, head), 4 waves.
// K/V from packed per-head dense tiles (coalesced vmem); partials merge in LDS.
// Grid 1-D MAXT*8, XCD-chunked decode: XCD x <-> head x (L2 locality).
// NOTE: all O[] indexing compile-time (rule #20).
// ---------------------------------------------------------------------------
__global__ __launch_bounds__(256) void attn_kernel(
        const u16* __restrict__ qkv, const u16* __restrict__ Kpack,
        const u16* __restrict__ Vpack,
        const u16* __restrict__ bias, u16* __restrict__ attn_out,
        const int* __restrict__ meta, int PN, int PT, int MAXT){
    __shared__ float sml[2][4][32];
    __shared__ float sfac[4][32];
    __shared__ float sLinv[32];
    __shared__ float sO[4][64][17];    // +1 pad: conflict-free merge

    // XCD-chunked bijective decode (gridDim.x = MAXT*8, divisible by 8)
    const int q8 = gridDim.x >> 3;
    const int work = ((int)blockIdx.x & 7)*q8 + ((int)blockIdx.x >> 3);
    const int h = work / MAXT;
    const int tile = work - h*MAXT;
    if (tile >= meta[0]) return;

    const int g    = meta[64 + tile];
    const int qt   = meta[64 + MAXT + tile];
    const int goff = meta[1+g], gend = meta[2+g];
    const int ng   = gend - goff;
    const int ntg  = (ng + 31) >> 5;
    const int qbase = goff + qt*32;
    const int pst  = meta[20+g];
    const int boffg= meta[40+g];

    const int tid = threadIdx.x;
    const int w = tid >> 6, lane = tid & 63;
    const int li = lane & 31, hi = lane >> 5;

    int qnode = qbase + li; if (qnode >= gend) qnode = gend - 1;
    const u16* qrow = qkv + (size_t)qnode*QKV_DIM + h*144;
    bf16x8 qf[9];
    #pragma unroll
    for (int kk = 0; kk < 9; kk++) qf[kk] = *(const bf16x8*)(qrow + kk*16 + hi*8);

    int jlr[16];
    #pragma unroll
    for (int r = 0; r < 16; r++) jlr[r] = (r & 3) + ((r >> 2) << 3) + (hi << 2);

    const u16* bbase = bias + ((size_t)boffg + (size_t)qt*ntg)*8192 + h*1024 + li;
    const u16* kgbase = Kpack + ((size_t)h*PN + pst + li)*144;
    const u16* vgbase = Vpack + (((size_t)h*PT + (pst >> 5))*144)*32;

    float mrun = -INFINITY, lrun = 0.f;
    f32x16 O[5];
    #pragma unroll
    for (int dt = 0; dt < 5; dt++)
        #pragma unroll
        for (int e = 0; e < 16; e++) O[dt][e] = 0.f;

    #pragma unroll 1
    for (int t = w; t < ntg; t += 4){
        const int j0 = t*32;
        // bias loads issued early, consumed after QK chain
        const u16* bt = bbase + (size_t)t*8192;
        u16 braw[16];
        #pragma unroll
        for (int r = 0; r < 16; r++) braw[r] = bt[jlr[r]*32];

        // QK^T: dense per-head K tile (lane li = key li, 288B row)
        const u16* krow = kgbase + (size_t)j0*144;
        f32x16 sacc;
        #pragma unroll
        for (int e = 0; e < 16; e++) sacc[e] = 0.f;
        #pragma unroll
        for (int kk = 0; kk < 9; kk++){
            bf16x8 kf = *(const bf16x8*)(krow + kk*16 + hi*8);
            sacc = __builtin_amdgcn_mfma_f32_32x32x16_bf16(kf, qf[kk], sacc, 0, 0, 0);
        }

        float sarr[16];
        #pragma unroll
        for (int r = 0; r < 16; r++){
            float sv = sacc[r]*HD_SCALE + bf2f(braw[r]);
            sarr[r] = ((j0 + jlr[r]) < ng) ? sv : -INFINITY;
        }

        float rmax = -INFINITY;
        #pragma unroll
        for (int r = 0; r < 16; r++) rmax = fmaxf(rmax, sarr[r]);
        rmax = fmaxf(rmax, __shfl_xor(rmax, 32));

        if (!__all(rmax <= mrun + 5.0f)){     // T13 defer-rescale
            float mnew = fmaxf(mrun, rmax);
            float alpha = exp2f((mrun - mnew)*LOG2E);
            lrun *= alpha;
            float ar[16];
            #pragma unroll
            for (int r = 0; r < 16; r++) ar[r] = __shfl(alpha, jlr[r]);
            #pragma unroll
            for (int dt = 0; dt < 5; dt++)
                #pragma unroll
                for (int r = 0; r < 16; r++) O[dt][r] *= ar[r];
            mrun = mnew;
        }

        float psum = 0.f;
        #pragma unroll
        for (int r = 0; r < 16; r++){
            float p = exp2f((sarr[r] - mrun)*LOG2E);
            sarr[r] = p; psum += p;
        }
        psum += __shfl_xor(psum, 32);
        lrun += psum;

        // pack P -> bf16 A-fragment (halves exchange)
        u32 cpk[8], opk[8];
        #pragma unroll
        for (int q = 0; q < 8; q++) cpk[q] = pack2(sarr[2*q], sarr[2*q+1]);
        #pragma unroll
        for (int q = 0; q < 8; q++) opk[q] = (u32)__shfl_xor((int)cpk[q], 32);
        u32x4 a0, a1;
        if (hi == 0){
            a0[0]=cpk[0]; a0[1]=cpk[1]; a0[2]=opk[0]; a0[3]=opk[1];
            a1[0]=cpk[4]; a1[1]=cpk[5]; a1[2]=opk[4]; a1[3]=opk[5];
        } else {
            a0[0]=opk[2]; a0[1]=opk[3]; a0[2]=cpk[2]; a0[3]=cpk[3];
            a1[0]=opk[6]; a1[1]=opk[7]; a1[2]=cpk[6]; a1[3]=cpk[7];
        }
        bf16x8 paf[2];
        paf[0] = __builtin_bit_cast(bf16x8, a0);
        paf[1] = __builtin_bit_cast(bf16x8, a1);

        // PV: dense 9KB V tile [144][32]; lane li = output dim d
        const u16* vtile = vgbase + (size_t)t*(144*32);
        #pragma unroll
        for (int dt = 0; dt < 5; dt++){
            int d = dt*32 + li;
            int dc = (d > 143) ? 143 : d;
            #pragma unroll
            for (int ks = 0; ks < 2; ks++){
                bf16x8 vf = *(const bf16x8*)(vtile + dc*32 + ((ks*2 + hi) << 3));
                O[dt] = __builtin_amdgcn_mfma_f32_32x32x16_bf16(paf[ks], vf, O[dt], 0, 0, 0);
            }
        }
    }

    // ---- cross-wave merge ----
    sml[0][w][li] = mrun;
    sml[1][w][li] = lrun;
    __syncthreads();
    if (tid < 32){
        int q = tid;
        float m0 = sml[0][0][q], m1 = sml[0][1][q];
        float m2 = sml[0][2][q], m3 = sml[0][3][q];
        float m = fmaxf(fmaxf(m0, m1), fmaxf(m2, m3));
        float f0 = exp2f((m0 - m)*LOG2E), f1 = exp2f((m1 - m)*LOG2E);
        float f2 = exp2f((m2 - m)*LOG2E), f3 = exp2f((m3 - m)*LOG2E);
        sfac[0][q] = f0; sfac[1][q] = f1; sfac[2][q] = f2; sfac[3][q] = f3;
        float L = f0*sml[1][0][q] + f1*sml[1][1][q] + f2*sml[1][2][q] + f3*sml[1][3][q];
        sLinv[q] = 1.0f / L;
    }
    __syncthreads();

    #pragma unroll              // MUST stay fully unrolled: O[dt] static index
    for (int dt = 0; dt < 5; dt++){
        #pragma unroll
        for (int r = 0; r < 16; r++) sO[w][lane][r] = O[dt][r];
        __syncthreads();
        if (w == (dt & 3)){
            int d = dt*32 + li;
            if (d < 144){
                #pragma unroll
                for (int r = 0; r < 16; r++){
                    int q = jlr[r];
                    float s = sfac[0][q]*sO[0][lane][r] + sfac[1][q]*sO[1][lane][r]
                            + sfac[2][q]*sO[2][lane][r] + sfac[3][q]*sO[3][lane][r];
                    if (qt*32 + q < ng)
                        attn_out[(size_t)(qbase + q)*F_DIM + h*144 + d] = f2bf(s * sLinv[q]);
                }
            }
        }
        __syncthreads();
    }
}

// ---------------------------------------------------------------------------
// y = LayerNorm(x + out) * gamma + beta  (in-place over d_out)
// ---------------------------------------------------------------------------
__global__ __launch_bounds__(256) void ln_kernel(const float* __restrict__ x,
                                                 float* __restrict__ io,
                                                 const float* __restrict__ gamma,
                                                 const float* __restrict__ beta){
    const int node = blockIdx.x;
    const float* xr = x  + (size_t)node*F_DIM;
    float* yr       = io + (size_t)node*F_DIM;
    const int t = threadIdx.x;
    float h[5]; float s = 0.f, ss = 0.f;
    #pragma unroll
    for (int i = 0; i < 5; i++){
        int idx = t + i*256;
        float v = 0.f;
        if (idx < F_DIM) v = xr[idx] + yr[idx];
        h[i] = v; s += v; ss += v*v;
    }
    #pragma unroll
    for (int o = 32; o > 0; o >>= 1){ s += __shfl_down(s, o); ss += __shfl_down(ss, o); }
    __shared__ float rs[4], rss[4];
    __shared__ float smu, srstd;
    if ((t & 63) == 0){ rs[t>>6] = s; rss[t>>6] = ss; }
    __syncthreads();
    if (t == 0){
        float S  = rs[0]+rs[1]+rs[2]+rs[3];
        float SS = rss[0]+rss[1]+rss[2]+rss[3];
        float mu = S * (1.f/F_DIM);
        float var = SS * (1.f/F_DIM) - mu*mu;
        smu = mu; srstd = rsqrtf(var + 1e-5f);
    }
    __syncthreads();
    float mu = smu, rstd = srstd;
    #pragma unroll
    for (int i = 0; i < 5; i++){
        int idx = t + i*256;
        if (idx < F_DIM) yr[idx] = (h[i]-mu)*rstd*gamma[idx] + beta[idx];
    }
}

// ---------------------------------------------------------------------------
extern "C" void kernel_launch(void* const* d_in, const int* in_sizes, int n_in,
                              void* d_out, int out_size, void* d_ws, size_t ws_size,
                              hipStream_t stream){
    const float* x     = (const float*)d_in[0];
    const float* pos   = (const float*)d_in[1];
    const float* Wqkv  = (const float*)d_in[2];
    const float* Wout  = (const float*)d_in[3];
    const float* rfreq = (const float*)d_in[4];
    const float* Wrope = (const float*)d_in[5];
    const float* gamma = (const float*)d_in[6];
    const float* beta  = (const float*)d_in[7];
    const int*   batch = (const int*)d_in[8];

    const int N  = in_sizes[0] / F_DIM;     // 8192
    const int PN = N + 512;                 // padded columns
    const int PT = PN / 32;                 // padded tiles
    const int MAXT = N/32 + 16;             // 272

    char* ws = (char*)d_ws;
    size_t off = 0;
    auto alloc = [&](size_t b){ size_t o = off; off += (b + 255) & ~(size_t)255; return o; };
    int* meta   = (int*)(ws + alloc((size_t)(64 + 2*MAXT)*sizeof(int)));
    u16* xb     = (u16*)(ws + alloc((size_t)N*F_DIM*2));        // reused as attn_out
    u16* wqkvT  = (u16*)(ws + alloc((size_t)QKV_DIM*F_DIM*2));
    u16* woutT  = (u16*)(ws + alloc((size_t)F_DIM*F_DIM*2));
    u16* qkv    = (u16*)(ws + alloc((size_t)N*QKV_DIM*2));
    u16* Kpack  = (u16*)(ws + alloc((size_t)8*PN*144*2));
    u16* Vpack  = (u16*)(ws + alloc((size_t)8*PT*144*32*2));
    u16* biasb  = (u16*)(ws + off);         // rest of workspace: bias blocks
    (void)ws_size; (void)n_in; (void)out_size;

    hipLaunchKernelGGL(setup_meta, dim3(1), dim3(64), 0, stream, batch, meta, N, MAXT);
    hipLaunchKernelGGL(cast_f32_bf16, dim3((N*F_DIM/4 + 255)/256), dim3(256), 0, stream,
                       x, xb, N*F_DIM/4);
    hipLaunchKernelGGL(transpose_cast, dim3(QKV_DIM/32, F_DIM/32), dim3(256), 0, stream,
                       Wqkv, wqkvT, F_DIM, QKV_DIM);
    hipLaunchKernelGGL(transpose_cast, dim3(F_DIM/32, F_DIM/32), dim3(256), 0, stream,
                       Wout, woutT, F_DIM, F_DIM);
    hipLaunchKernelGGL((gemm128<true>), dim3(N/128, QKV_DIM/128), dim3(256), 0, stream,
                       xb, wqkvT, (void*)qkv, N, QKV_DIM, F_DIM);
    hipLaunchKernelGGL(pack_k, dim3(N/32, 8), dim3(256), 0, stream,
                       qkv, Kpack, batch, meta, PN);
    hipLaunchKernelGGL(pack_v, dim3(N/32, 5, 8), dim3(256), 0, stream,
                       qkv, Vpack, batch, meta, PT);
    hipLaunchKernelGGL(bias_kernel, dim3(2048), dim3(256), 0, stream,
                       pos, rfreq, Wrope, meta, biasb);
    hipLaunchKernelGGL(attn_kernel, dim3(MAXT*8), dim3(256), 0, stream,
                       qkv, Kpack, Vpack, biasb, xb, meta, PN, PT, MAXT);
    hipLaunchKernelGGL((gemm128<false>), dim3(N/128, F_DIM/128), dim3(256), 0, stream,
                       xb, woutT, d_out, N, F_DIM, F_DIM);
    hipLaunchKernelGGL(ln_kernel, dim3(N), dim3(256), 0, stream,
                       x, (float*)d_out, gamma, beta);
}

// Round 7
// 375.252 us; speedup vs baseline: 1.4133x; 1.2492x over previous
//
#include <hip/hip_runtime.h>

typedef unsigned short u16;
typedef unsigned int   u32;
typedef __attribute__((ext_vector_type(8)))  __bf16 bf16x8;
typedef __attribute__((ext_vector_type(4)))  float  f32x4;
typedef __attribute__((ext_vector_type(16))) float  f32x16;
typedef __attribute__((ext_vector_type(4)))  u32    u32x4;

#define F_DIM   1152
#define QKV_DIM 3456
#define HD_SCALE 0.083333333333333333f   // 1/sqrt(144)
#define LOG2E    1.4426950408889634f
#define MAX4    80                        // >= sum ceil(ntg/4) over graphs

static __device__ __forceinline__ u16 f2bf(float f){
    u32 u = __builtin_bit_cast(u32, f);
    u32 r = u + 0x7fffu + ((u >> 16) & 1u);   // RNE
    return (u16)(r >> 16);
}
static __device__ __forceinline__ float bf2f(u16 h){
    u32 u = ((u32)h) << 16;
    return __builtin_bit_cast(float, u);
}
static __device__ __forceinline__ u32 pack2(float a, float b){
    return (u32)f2bf(a) | ((u32)f2bf(b) << 16);
}

typedef __attribute__((address_space(1))) void gvoid;
typedef __attribute__((address_space(3))) void lvoid;
static __device__ __forceinline__ void gload16(const u16* g, u16* l){
    __builtin_amdgcn_global_load_lds((gvoid*)g, (lvoid*)l, 16, 0, 0);
}

// ---------------------------------------------------------------------------
// meta: [0]=count4  [1..17]=graph offsets  [20..36]=padded col starts
//       [40..56]=bias block offsets  [64+i]=tile4 graph  [64+MAX4+i]=tile4 q4
// ---------------------------------------------------------------------------
__global__ void setup_meta(const int* __restrict__ batch, int* __restrict__ meta, int N){
    int t = threadIdx.x;
    if (t <= 16){
        int lo = 0, hi = N;
        while (lo < hi){ int mid = (lo+hi)>>1; if (batch[mid] < t) lo = mid+1; else hi = mid; }
        meta[1+t] = lo;
    }
    __syncthreads();
    if (t == 0){
        int ps = 0, bcnt = 0, cnt4 = 0;
        for (int g = 0; g < 16; g++){
            int ng = meta[2+g] - meta[1+g];
            meta[20+g] = ps;
            meta[40+g] = bcnt;
            int nt = (ng + 31) / 32;
            ps += nt * 32;
            bcnt += nt * nt;
            int nt4 = (nt + 3) / 4;
            for (int q4 = 0; q4 < nt4; q4++){
                meta[64 + cnt4] = g;
                meta[64 + MAX4 + cnt4] = q4;
                cnt4++;
            }
        }
        meta[36] = ps;
        meta[56] = bcnt;
        meta[0]  = cnt4;
    }
}

__global__ __launch_bounds__(256) void cast_f32_bf16(const float* __restrict__ in,
                                                     u16* __restrict__ out, int n4){
    int i = blockIdx.x*256 + threadIdx.x;
    if (i < n4){
        float4 v = ((const float4*)in)[i];
        ((ushort4*)out)[i] = make_ushort4(f2bf(v.x), f2bf(v.y), f2bf(v.z), f2bf(v.w));
    }
}

__global__ __launch_bounds__(256) void transpose_cast(const float* __restrict__ in,
                                                      u16* __restrict__ out, int R, int C){
    __shared__ float tile[32][33];
    int c0 = blockIdx.x*32, r0 = blockIdx.y*32;
    int tx = threadIdx.x & 31, ty = threadIdx.x >> 5;
    #pragma unroll
    for (int yy = ty; yy < 32; yy += 8){
        int r = r0+yy, c = c0+tx;
        tile[yy][tx] = (r < R && c < C) ? in[(size_t)r*C + c] : 0.f;
    }
    __syncthreads();
    #pragma unroll
    for (int yy = ty; yy < 32; yy += 8){
        int oc = c0+yy, orr = r0+tx;
        if (oc < C && orr < R) out[(size_t)oc*R + orr] = f2bf(tile[tx][yy]);
    }
}

// ---------------------------------------------------------------------------
// C[M,Ncols] = A[M,K] * Bt[Ncols,K]^T ; 128x128 tile, BK=32, global_load_lds,
// XCD-aware bijective swizzle.
// ---------------------------------------------------------------------------
template<bool OUT_BF16>
__global__ __launch_bounds__(256) void gemm128(const u16* __restrict__ A,
                                               const u16* __restrict__ Bt,
                                               void* __restrict__ Cp,
                                               int M, int Ncols, int K){
    __shared__ u16 sA[128*32];
    __shared__ u16 sB[128*32];
    const int nwg = gridDim.x * gridDim.y;
    int orig = blockIdx.y * gridDim.x + blockIdx.x;
    int qq = nwg >> 3, rr = nwg & 7;
    int xcd = orig & 7, pos = orig >> 3;
    int nid = (xcd < rr ? xcd*(qq+1) : rr*(qq+1) + (xcd-rr)*qq) + pos;
    const int bm = (nid % gridDim.x) * 128, bn = (nid / gridDim.x) * 128;

    const int t = threadIdx.x;
    const int lane = t & 63, w = t >> 6;
    const int wr = w >> 1, wc = w & 1;
    const int fr = lane & 15, fq = lane >> 4;

    f32x16 accf[4];
    #pragma unroll
    for (int m = 0; m < 4; m++)
        #pragma unroll
        for (int e = 0; e < 16; e++) accf[m][e] = 0.f;

    const u16* aptr = A  + (size_t)(bm + (t>>2))*K + ((t&3)<<3);
    const u16* bptr = Bt + (size_t)(bn + (t>>2))*K + ((t&3)<<3);
    const size_t half = (size_t)64*K;

    for (int k0 = 0; k0 < K; k0 += 32){
        __syncthreads();
        gload16(aptr + k0,        &sA[t*8]);
        gload16(aptr + k0 + half, &sA[2048 + t*8]);
        gload16(bptr + k0,        &sB[t*8]);
        gload16(bptr + k0 + half, &sB[2048 + t*8]);
        __syncthreads();
        bf16x8 af[4], bfr[4];
        #pragma unroll
        for (int m = 0; m < 4; m++) af[m]  = *(const bf16x8*)(&sA[(wr*64 + m*16 + fr)*32 + fq*8]);
        #pragma unroll
        for (int n = 0; n < 4; n++) bfr[n] = *(const bf16x8*)(&sB[(wc*64 + n*16 + fr)*32 + fq*8]);
        #pragma unroll
        for (int m = 0; m < 4; m++){
            #pragma unroll
            for (int n = 0; n < 4; n++){
                f32x4 a; a[0]=accf[m][n*4+0]; a[1]=accf[m][n*4+1]; a[2]=accf[m][n*4+2]; a[3]=accf[m][n*4+3];
                a = __builtin_amdgcn_mfma_f32_16x16x32_bf16(af[m], bfr[n], a, 0, 0, 0);
                accf[m][n*4+0]=a[0]; accf[m][n*4+1]=a[1]; accf[m][n*4+2]=a[2]; accf[m][n*4+3]=a[3];
            }
        }
    }
    #pragma unroll
    for (int m = 0; m < 4; m++)
        #pragma unroll
        for (int n = 0; n < 4; n++)
            #pragma unroll
            for (int r = 0; r < 4; r++){
                int row = bm + wr*64 + m*16 + fq*4 + r;
                int col = bn + wc*64 + n*16 + fr;
                float v = accf[m][n*4+r];
                if (OUT_BF16) ((u16*)Cp)[(size_t)row*Ncols + col] = f2bf(v);
                else          ((float*)Cp)[(size_t)row*Ncols + col] = v;
            }
}

// ---------------------------------------------------------------------------
// Vpack[h][ptile][d=144][key&31] = v[node][h*144+d] ; dense 9KB per KV tile.
// Unwritten pad columns hold garbage; killed by P=0 in PV.
// ---------------------------------------------------------------------------
__global__ __launch_bounds__(256) void pack_v(const u16* __restrict__ qkv,
                                              u16* __restrict__ Vpack,
                                              const int* __restrict__ batch,
                                              const int* __restrict__ meta,
                                              int PT){
    __shared__ u16 tile[32][33];
    int nt0 = blockIdx.x*32, dt0 = blockIdx.y*32, h = blockIdx.z;
    int tx = threadIdx.x & 31, ty = threadIdx.x >> 5;
    #pragma unroll
    for (int yy = ty; yy < 32; yy += 8){
        int node = nt0+yy, d = dt0+tx;
        tile[yy][tx] = (d < 144) ? qkv[(size_t)node*QKV_DIM + 2*F_DIM + h*144 + d] : (u16)0;
    }
    __syncthreads();
    int node = nt0 + tx;
    int g = batch[node];
    int col = meta[20+g] + (node - meta[1+g]);
    int pt = col >> 5, cl = col & 31;
    #pragma unroll
    for (int yy = ty; yy < 32; yy += 8){
        int d = dt0+yy;
        if (d < 144) Vpack[(((size_t)h*PT + pt)*144 + d)*32 + cl] = tile[tx][yy];
    }
}

// ---------------------------------------------------------------------------
// Fourier bias precompute, cos shared across heads.
// bias[block(g,qt,jt)*8192 + h*1024 + j*32 + i]  (bf16)
// ---------------------------------------------------------------------------
__global__ __launch_bounds__(256) void bias_kernel(const float* __restrict__ pos,
                                                   const float* __restrict__ rfreq,
                                                   const float* __restrict__ Wrope,
                                                   const int* __restrict__ meta,
                                                   u16* __restrict__ bias){
    float absf[16], w[16][8];
    #pragma unroll
    for (int r = 0; r < 16; r++){
        absf[r] = fabsf(rfreq[r]);
        #pragma unroll
        for (int h = 0; h < 8; h++) w[r][h] = Wrope[r*8 + h];
    }
    const int total = meta[56];
    const int t = threadIdx.x;
    for (int bb = blockIdx.x; bb < total; bb += gridDim.x){
        int g = 0;
        while (meta[40 + g + 1] <= bb) g++;
        int rem  = bb - meta[40 + g];
        int goff = meta[1+g];
        int ng   = meta[2+g] - goff;
        int ntg  = (ng + 31) >> 5;
        int qt   = rem / ntg;
        int jt   = rem - qt*ntg;
        size_t base = (size_t)bb * 8192;
        #pragma unroll
        for (int pp = 0; pp < 4; pp++){
            int p = t + pp*256;
            int qn = goff + qt*32 + (p & 31);  if (qn >= goff + ng) qn = goff + ng - 1;
            int kn = goff + jt*32 + (p >> 5);  if (kn >= goff + ng) kn = goff + ng - 1;
            float dx = pos[qn*3+0] - pos[kn*3+0];
            float dy = pos[qn*3+1] - pos[kn*3+1];
            float dz = pos[qn*3+2] - pos[kn*3+2];
            float d  = sqrtf(dx*dx + dy*dy + dz*dz);
            float b[8];
            #pragma unroll
            for (int h = 0; h < 8; h++) b[h] = 0.f;
            #pragma unroll
            for (int r = 0; r < 16; r++){
                float c = __cosf(d * absf[r]);
                #pragma unroll
                for (int h = 0; h < 8; h++) b[h] = fmaf(c, w[r][h], b[h]);
            }
            #pragma unroll
            for (int h = 0; h < 8; h++)
                bias[base + h*1024 + p] = f2bf(b[h]);
        }
    }
}

// ---------------------------------------------------------------------------
// Flash attention: block = 4 waves = 4 consecutive q-tiles of one (graph,head).
// K, V AND bias staged in LDS via global_load_lds, double-buffered.
// Grid 1-D MAX4*8, h = bid&7 -> head-per-XCD L2 locality.
// ---------------------------------------------------------------------------
__global__ __launch_bounds__(256) void attn_kernel(
        const u16* __restrict__ qkv, const u16* __restrict__ Vpack,
        const u16* __restrict__ bias, u16* __restrict__ attn_out,
        const int* __restrict__ meta, int PT){
    __shared__ u16 sK[2][4864];   // 32 rows x 19 chunks(16B) = 304B/row
    __shared__ u16 sV[2][4608];   // 144 rows x 64B, chunk-XOR swizzle
    __shared__ u16 sB[2][4096];   // 4 qtiles x 1024 bf16 bias
    const int h = blockIdx.x & 7, t4 = blockIdx.x >> 3;
    if (t4 >= meta[0]) return;
    const int g    = meta[64 + t4];
    const int q4   = meta[64 + MAX4 + t4];
    const int goff = meta[1+g], gend = meta[2+g];
    const int ng   = gend - goff;
    const int ntg  = (ng + 31) >> 5;
    const int pst  = meta[20+g];
    const int boffg= meta[40+g];

    const int tid = threadIdx.x;
    const int w = tid >> 6, lane = tid & 63;
    const int li = lane & 31, hi = lane >> 5;
    const int qt = q4*4 + w;
    const int qbase = goff + qt*32;

    // ---- staging sources (advance per tile) ----
    const u16* kSrc[3]; int kDst[3];
    #pragma unroll
    for (int p = 0; p < 3; p++){
        int idx = p*256 + tid;
        if (idx > 607) idx = 607;
        int row = idx / 19;
        int c   = idx - row*19;
        if (c == 18) c = 0;                 // dup chunk0 into pad slot
        kSrc[p] = qkv + (size_t)(goff + row)*QKV_DIM + F_DIM + h*144 + c*8;
        kDst[p] = (p*256 + tid)*8;
    }
    const u16* vSrc[3]; int vDst[3];
    const u16* vtile0 = Vpack + ((size_t)h*PT + (pst >> 5))*4608;
    #pragma unroll
    for (int p = 0; p < 3; p++){
        int idx = p*256 + tid;
        if (idx > 575) idx = 575;
        int d = idx >> 2, c = idx & 3;
        vSrc[p] = vtile0 + d*32 + ((c ^ (d & 3)) << 3);   // pre-swizzled source
        vDst[p] = (p*256 + tid)*8;
    }
    const u16* bSrc[2];
    #pragma unroll
    for (int p = 0; p < 2; p++){
        int idx = p*256 + tid;               // 0..511 chunks of 16B
        int qq = idx >> 7;                   // which of 4 qtiles
        int pc = idx & 127;                  // chunk within 2KB
        int qtS = q4*4 + qq; if (qtS > ntg-1) qtS = ntg-1;
        bSrc[p] = bias + ((size_t)boffg + (size_t)qtS*ntg)*8192 + h*1024 + pc*8;
    }
    auto STAGE = [&](int buf){
        gload16(kSrc[0], &sK[buf][kDst[0]]);
        gload16(kSrc[1], &sK[buf][kDst[1]]);
        if (tid < 96) gload16(kSrc[2], &sK[buf][kDst[2]]);
        gload16(vSrc[0], &sV[buf][vDst[0]]);
        gload16(vSrc[1], &sV[buf][vDst[1]]);
        if (tid < 64) gload16(vSrc[2], &sV[buf][vDst[2]]);
        gload16(bSrc[0], &sB[buf][tid*8]);
        gload16(bSrc[1], &sB[buf][(256 + tid)*8]);
        kSrc[0] += 32*QKV_DIM; kSrc[1] += 32*QKV_DIM; kSrc[2] += 32*QKV_DIM;
        vSrc[0] += 4608; vSrc[1] += 4608; vSrc[2] += 4608;
        bSrc[0] += 8192; bSrc[1] += 8192;
    };

    // ---- per-wave state ----
    int qnode = qbase + li; if (qnode >= gend) qnode = gend - 1;
    const u16* qrow = qkv + (size_t)qnode*QKV_DIM + h*144;
    bf16x8 qf[9];
    #pragma unroll
    for (int kk = 0; kk < 9; kk++) qf[kk] = *(const bf16x8*)(qrow + kk*16 + hi*8);

    int jlr[16];
    #pragma unroll
    for (int r = 0; r < 16; r++) jlr[r] = (r & 3) + ((r >> 2) << 3) + (hi << 2);

    float mrun = -INFINITY, lrun = 0.f;
    f32x16 O[5];
    #pragma unroll
    for (int dt = 0; dt < 5; dt++)
        #pragma unroll
        for (int e = 0; e < 16; e++) O[dt][e] = 0.f;

    STAGE(0);
    __syncthreads();

    #pragma unroll 1
    for (int t = 0; t < ntg; t++){
        const int cur = t & 1;
        if (t+1 < ntg) STAGE(cur^1);

        // bias from LDS
        u16 braw[16];
        #pragma unroll
        for (int r = 0; r < 16; r++) braw[r] = sB[cur][w*1024 + jlr[r]*32 + li];

        // QK^T from LDS K
        const u16* sKc = &sK[cur][0];
        f32x16 sacc;
        #pragma unroll
        for (int e = 0; e < 16; e++) sacc[e] = 0.f;
        #pragma unroll
        for (int kk = 0; kk < 9; kk++){
            bf16x8 kf = *(const bf16x8*)(sKc + li*152 + kk*16 + hi*8);
            sacc = __builtin_amdgcn_mfma_f32_32x32x16_bf16(kf, qf[kk], sacc, 0, 0, 0);
        }

        const int j0 = t*32;
        float sarr[16];
        #pragma unroll
        for (int r = 0; r < 16; r++){
            float sv = sacc[r]*HD_SCALE + bf2f(braw[r]);
            sarr[r] = ((j0 + jlr[r]) < ng) ? sv : -INFINITY;
        }

        float rmax = -INFINITY;
        #pragma unroll
        for (int r = 0; r < 16; r++) rmax = fmaxf(rmax, sarr[r]);
        rmax = fmaxf(rmax, __shfl_xor(rmax, 32));

        if (!__all(rmax <= mrun + 5.0f)){     // T13 defer-rescale
            float mnew = fmaxf(mrun, rmax);
            float alpha = exp2f((mrun - mnew)*LOG2E);
            lrun *= alpha;
            float ar[16];
            #pragma unroll
            for (int r = 0; r < 16; r++) ar[r] = __shfl(alpha, jlr[r]);
            #pragma unroll
            for (int dt = 0; dt < 5; dt++)
                #pragma unroll
                for (int r = 0; r < 16; r++) O[dt][r] *= ar[r];
            mrun = mnew;
        }

        float psum = 0.f;
        #pragma unroll
        for (int r = 0; r < 16; r++){
            float p = exp2f((sarr[r] - mrun)*LOG2E);
            sarr[r] = p; psum += p;
        }
        psum += __shfl_xor(psum, 32);
        lrun += psum;

        // pack P -> bf16 A-fragment (halves exchange)
        u32 cpk[8], opk[8];
        #pragma unroll
        for (int q = 0; q < 8; q++) cpk[q] = pack2(sarr[2*q], sarr[2*q+1]);
        #pragma unroll
        for (int q = 0; q < 8; q++) opk[q] = (u32)__shfl_xor((int)cpk[q], 32);
        u32x4 a0, a1;
        if (hi == 0){
            a0[0]=cpk[0]; a0[1]=cpk[1]; a0[2]=opk[0]; a0[3]=opk[1];
            a1[0]=cpk[4]; a1[1]=cpk[5]; a1[2]=opk[4]; a1[3]=opk[5];
        } else {
            a0[0]=opk[2]; a0[1]=opk[3]; a0[2]=cpk[2]; a0[3]=cpk[3];
            a1[0]=opk[6]; a1[1]=opk[7]; a1[2]=cpk[6]; a1[3]=cpk[7];
        }
        bf16x8 paf[2];
        paf[0] = __builtin_bit_cast(bf16x8, a0);
        paf[1] = __builtin_bit_cast(bf16x8, a1);

        // PV from LDS V (swizzled reads)
        const u16* sVc = &sV[cur][0];
        #pragma unroll
        for (int dt = 0; dt < 5; dt++){
            int d = dt*32 + li;
            int dc = (d > 143) ? 143 : d;
            #pragma unroll
            for (int ks = 0; ks < 2; ks++){
                int c = ks*2 + hi;
                bf16x8 vf = *(const bf16x8*)(sVc + dc*32 + ((c ^ (dc & 3)) << 3));
                O[dt] = __builtin_amdgcn_mfma_f32_32x32x16_bf16(paf[ks], vf, O[dt], 0, 0, 0);
            }
        }
        __syncthreads();
    }

    if (qt < ntg){
        float lr[16];
        #pragma unroll
        for (int r = 0; r < 16; r++) lr[r] = 1.0f / __shfl(lrun, jlr[r]);
        #pragma unroll
        for (int dt = 0; dt < 5; dt++){
            int d = dt*32 + li;
            if (d < 144){
                #pragma unroll
                for (int r = 0; r < 16; r++){
                    int qi = jlr[r];
                    if (qt*32 + qi < ng)
                        attn_out[(size_t)(qbase + qi)*F_DIM + h*144 + d] = f2bf(O[dt][r]*lr[r]);
                }
            }
        }
    }
}

// ---------------------------------------------------------------------------
// y = LayerNorm(x + out) * gamma + beta  (in-place over d_out)
// ---------------------------------------------------------------------------
__global__ __launch_bounds__(256) void ln_kernel(const float* __restrict__ x,
                                                 float* __restrict__ io,
                                                 const float* __restrict__ gamma,
                                                 const float* __restrict__ beta){
    const int node = blockIdx.x;
    const float* xr = x  + (size_t)node*F_DIM;
    float* yr       = io + (size_t)node*F_DIM;
    const int t = threadIdx.x;
    float h[5]; float s = 0.f, ss = 0.f;
    #pragma unroll
    for (int i = 0; i < 5; i++){
        int idx = t + i*256;
        float v = 0.f;
        if (idx < F_DIM) v = xr[idx] + yr[idx];
        h[i] = v; s += v; ss += v*v;
    }
    #pragma unroll
    for (int o = 32; o > 0; o >>= 1){ s += __shfl_down(s, o); ss += __shfl_down(ss, o); }
    __shared__ float rs[4], rss[4];
    __shared__ float smu, srstd;
    if ((t & 63) == 0){ rs[t>>6] = s; rss[t>>6] = ss; }
    __syncthreads();
    if (t == 0){
        float S  = rs[0]+rs[1]+rs[2]+rs[3];
        float SS = rss[0]+rss[1]+rss[2]+rss[3];
        float mu = S * (1.f/F_DIM);
        float var = SS * (1.f/F_DIM) - mu*mu;
        smu = mu; srstd = rsqrtf(var + 1e-5f);
    }
    __syncthreads();
    float mu = smu, rstd = srstd;
    #pragma unroll
    for (int i = 0; i < 5; i++){
        int idx = t + i*256;
        if (idx < F_DIM) yr[idx] = (h[i]-mu)*rstd*gamma[idx] + beta[idx];
    }
}

// ---------------------------------------------------------------------------
extern "C" void kernel_launch(void* const* d_in, const int* in_sizes, int n_in,
                              void* d_out, int out_size, void* d_ws, size_t ws_size,
                              hipStream_t stream){
    const float* x     = (const float*)d_in[0];
    const float* pos   = (const float*)d_in[1];
    const float* Wqkv  = (const float*)d_in[2];
    const float* Wout  = (const float*)d_in[3];
    const float* rfreq = (const float*)d_in[4];
    const float* Wrope = (const float*)d_in[5];
    const float* gamma = (const float*)d_in[6];
    const float* beta  = (const float*)d_in[7];
    const int*   batch = (const int*)d_in[8];

    const int N  = in_sizes[0] / F_DIM;     // 8192
    const int PN = N + 512;                 // padded columns
    const int PT = PN / 32;                 // padded tiles

    char* ws = (char*)d_ws;
    size_t off = 0;
    auto alloc = [&](size_t b){ size_t o = off; off += (b + 255) & ~(size_t)255; return o; };
    int* meta   = (int*)(ws + alloc((size_t)(64 + 2*MAX4 + 64)*sizeof(int)));
    u16* xb     = (u16*)(ws + alloc((size_t)N*F_DIM*2));        // reused as attn_out
    u16* wqkvT  = (u16*)(ws + alloc((size_t)QKV_DIM*F_DIM*2));
    u16* woutT  = (u16*)(ws + alloc((size_t)F_DIM*F_DIM*2));
    u16* qkv    = (u16*)(ws + alloc((size_t)N*QKV_DIM*2));
    u16* Vpack  = (u16*)(ws + alloc((size_t)8*PT*144*32*2));
    u16* biasb  = (u16*)(ws + off);         // rest of workspace: bias blocks
    (void)ws_size; (void)n_in; (void)out_size;

    hipLaunchKernelGGL(setup_meta, dim3(1), dim3(64), 0, stream, batch, meta, N);
    hipLaunchKernelGGL(cast_f32_bf16, dim3((N*F_DIM/4 + 255)/256), dim3(256), 0, stream,
                       x, xb, N*F_DIM/4);
    hipLaunchKernelGGL(transpose_cast, dim3(QKV_DIM/32, F_DIM/32), dim3(256), 0, stream,
                       Wqkv, wqkvT, F_DIM, QKV_DIM);
    hipLaunchKernelGGL(transpose_cast, dim3(F_DIM/32, F_DIM/32), dim3(256), 0, stream,
                       Wout, woutT, F_DIM, F_DIM);
    hipLaunchKernelGGL((gemm128<true>), dim3(N/128, QKV_DIM/128), dim3(256), 0, stream,
                       xb, wqkvT, (void*)qkv, N, QKV_DIM, F_DIM);
    hipLaunchKernelGGL(pack_v, dim3(N/32, 5, 8), dim3(256), 0, stream,
                       qkv, Vpack, batch, meta, PT);
    hipLaunchKernelGGL(bias_kernel, dim3(2048), dim3(256), 0, stream,
                       pos, rfreq, Wrope, meta, biasb);
    hipLaunchKernelGGL(attn_kernel, dim3(MAX4*8), dim3(256), 0, stream,
                       qkv, Vpack, biasb, xb, meta, PT);
    hipLaunchKernelGGL((gemm128<false>), dim3(N/128, F_DIM/128), dim3(256), 0, stream,
                       xb, woutT, d_out, N, F_DIM, F_DIM);
    hipLaunchKernelGGL(ln_kernel, dim3(N), dim3(256), 0, stream,
                       x, (float*)d_out, gamma, beta);
}